// Round 5
// baseline (1764.616 us; speedup 1.0000x reference)
//
#include <hip/hip_runtime.h>
#include <math.h>

#define MULT 32
#define NSPEC 10
#define NGRAPH 16
#define NBANK 64          /* stat replication banks (tp_kernel) */
#define NCBANK 16         /* cnt replication banks (count_kernel) */
#define INV_SC 0.05590169943749474f   /* 1/sqrt(32*10) */
#define INV32S 0.17677669529663687f   /* 1/sqrt(32) */

typedef unsigned short u16;
typedef __bf16 v8bf __attribute__((ext_vector_type(8)));
typedef float v4f __attribute__((ext_vector_type(4)));
typedef unsigned int v4u_t __attribute__((ext_vector_type(4)));

__device__ __forceinline__ u16 f2bf(float f) {
    unsigned int u = __builtin_bit_cast(unsigned int, f);
    unsigned int r = u + 0x7fffu + ((u >> 16) & 1u);
    return (u16)(r >> 16);
}

__device__ __forceinline__ v8bf frag16(const u16* p) {
    return __builtin_bit_cast(v8bf, *(const v4u_t*)p);
}

#define MFMA(a, b, c) __builtin_amdgcn_mfma_f32_16x16x32_bf16(a, b, c, 0, 0, 0)

// ---------------------------------------------------------------------------
// small utility kernels
// ---------------------------------------------------------------------------
__global__ void zero_kernel(float* __restrict__ p, int n) {
    int i = blockIdx.x * 256 + threadIdx.x;
    if (i < n) p[i] = 0.0f;
}

__global__ void count_kernel(const int* __restrict__ batch, float* __restrict__ cntb, int N) {
    __shared__ int bins[NGRAPH];
    int t = threadIdx.x;
    if (t < NGRAPH) bins[t] = 0;
    __syncthreads();
    int i = blockIdx.x * 256 + t;
    if (i < N) atomicAdd(&bins[batch[i]], 1);
    __syncthreads();
    int bank = blockIdx.x & (NCBANK - 1);
    if (t < NGRAPH && bins[t] > 0) atomicAdd(&cntb[bank * NGRAPH + t], (float)bins[t]);
}

// ---------------------------------------------------------------------------
// effective-weight precompute (fp32):
//  Weff[path,b][a,bb,z], path: 0=000, 1=110, 2=011, 3=101
// ---------------------------------------------------------------------------
__global__ void stageA_kernel(const float* __restrict__ w000, const float* __restrict__ w110,
                              const float* __restrict__ w011, const float* __restrict__ w101,
                              const float* __restrict__ lp0, const float* __restrict__ lp1,
                              float* __restrict__ tmp1) {
    int gid = blockIdx.x * 256 + threadIdx.x;
    int tslot = gid >> 15;
    int e = gid & 32767;
    int z = e & 31;
    int uv = e >> 5;
    int b = tslot >> 2, path = tslot & 3;
    const float* W = (path == 0 ? w000 : path == 1 ? w110 : path == 2 ? w011 : w101) + b * 32768;
    const float* L = ((path == 0 || path == 1) ? lp0 : lp1) + b * 1024;
    float scale = (path == 1) ? (1.0f / (8192.0f * 1.7320508075688772f)) : (1.0f / 8192.0f);
    const float* wr = W + uv * 32;
    float acc = 0.0f;
    for (int w = 0; w < 32; ++w) acc += wr[w] * L[w * 32 + z];
    tmp1[gid] = acc * scale;
}

__global__ void stageB_kernel(const float* __restrict__ ul0, const float* __restrict__ ul1,
                              const float* __restrict__ tmp1, float* __restrict__ tmp2) {
    int gid = blockIdx.x * 256 + threadIdx.x;
    int tslot = gid >> 15;
    int e = gid & 32767;
    int z = e & 31;
    int bb = (e >> 5) & 31;
    int u = e >> 10;
    int b = tslot >> 2, path = tslot & 3;
    const float* U = ((path == 0 || path == 3) ? ul0 : ul1) + b * 1024;
    const float* in = tmp1 + (size_t)tslot * 32768 + u * 1024 + z;
    float acc = 0.0f;
    for (int v = 0; v < 32; ++v) acc += U[bb * 32 + v] * in[v * 32];
    tmp2[gid] = acc;
}

__global__ void stageC_kernel(const float* __restrict__ hl0, const float* __restrict__ hl1,
                              const float* __restrict__ tmp2, float* __restrict__ Weff) {
    int gid = blockIdx.x * 256 + threadIdx.x;
    int tslot = gid >> 15;
    int e = gid & 32767;
    int z = e & 31;
    int bb = (e >> 5) & 31;
    int a = e >> 10;
    int b = tslot >> 2, path = tslot & 3;
    const float* H = ((path == 0 || path == 2) ? hl0 : hl1) + b * 1024;
    const float* in = tmp2 + (size_t)tslot * 32768 + bb * 32 + z;
    float acc = 0.0f;
    for (int u = 0; u < 32; ++u) acc += H[a * 32 + u] * in[u * 1024];
    Weff[gid] = acc;
}

// ---------------------------------------------------------------------------
// pack kernel: fp32 Weff / sc weights -> bf16, B-frag layouts (linear = col*32+k)
// per-b flat layout (151552 u16):
//  [0,32768):        W000T col=bb*32+z, k=a
//  [32768,65536):    W011T col=bb*32+z, k=a
//  [65536,98304):    W101T col=a*32+z,  k=bb
//  [98304,131072):   W110X col=a*32+z,  k=bb
//  [131072,141312):  WSC0P [s][col=z][k=a]  (x INV_SC)
//  [141312,151552):  WSC1P [s][col=z][k=a]  (x INV_SC)
// ---------------------------------------------------------------------------
__global__ void pack_kernel(const float* __restrict__ Weff,
                            const float* __restrict__ sc_w0, const float* __restrict__ sc_w1,
                            u16* __restrict__ packs, int total) {
    int gid = blockIdx.x * 256 + threadIdx.x;
    if (gid >= total) return;
    int b = gid / 151552;
    int e = gid - b * 151552;
    float v;
    if (e < 131072) {
        int which = e >> 15;          // 0:000 1:011 2:101 3:110
        int e2 = e & 32767;
        int k = e2 & 31;
        int z = (e2 >> 5) & 31;
        int hi = e2 >> 10;
        int path = (which == 0) ? 0 : (which == 1) ? 2 : (which == 2) ? 3 : 1;
        int a  = (which < 2) ? k  : hi;
        int bb = (which < 2) ? hi : k;
        v = Weff[(size_t)((b * 4 + path) * 32 + a) * 1024 + bb * 32 + z];
    } else {
        int e2 = e - 131072;
        int which = e2 / 10240;
        int e3 = e2 - which * 10240;
        int s = e3 >> 10, z = (e3 >> 5) & 31, a = e3 & 31;
        const float* S = which ? sc_w1 : sc_w0;
        v = S[(size_t)b * 10240 + a * 320 + s * 32 + z] * INV_SC;
    }
    packs[gid] = f2bf(v);
}

// ---------------------------------------------------------------------------
// MFMA TP + self-connection + stats kernel.  One WG (4 waves) per 16 nodes.
// R2 structure; the only change: each path section batch-loads its 16 weight
// fragments into 16 individually-NAMED v8bf scalars (no arrays -> nothing can
// demote to scratch), putting 16 independent global_load_dwordx4 in flight
// before any consumer.  Path 110 loads weights once, reused across 3 comps.
// waves_per_eu(3,4): ~170-VGPR budget, no spill at ~130 live.
// ---------------------------------------------------------------------------
__attribute__((amdgpu_waves_per_eu(3, 4)))
__global__ __launch_bounds__(256)
void tp_kernel(const float* __restrict__ hidden_b, const float* __restrict__ up,
               const u16* __restrict__ pk,
               const float* __restrict__ lp_b0,
               const int* __restrict__ species, const int* __restrict__ batch,
               float* __restrict__ S1b, float* __restrict__ S2b, float* __restrict__ V2b,
               float* __restrict__ zout, int N) {
    constexpr int OFF_000 = 0, OFF_011 = 32768, OFF_101 = 65536, OFF_110 = 98304;
    constexpr int OFF_SC0 = 131072, OFF_SC1 = 141312;

    __shared__ __align__(16) char smem[33792];
    __shared__ int spec_l[16];
    __shared__ int bat_l[16];
    __shared__ float gs1[NGRAPH], gs2[NGRAPH], gv2[NGRAPH];

    u16* sh_bf = (u16*)smem;                 // [16][40] bf16, A-layout
    u16* su_bf = (u16*)(smem + 1280);        // [16][40]
    u16* vu_bf = (u16*)(smem + 2560);        // [3][16][40]
    u16* vh_bf = (u16*)(smem + 6400);        // [3][16][40]
    float* suT = (float*)(smem + 10240);     // [32 bb][16 n] fp32 (Y)
    float* vuT = (float*)(smem + 12288);     // [3][32][16]
    float* vhT = (float*)(smem + 18432);     // [3][32][16]
    float* red = (float*)smem;               // [4][16][132] fp32 (epilogue overlay)

    const int t = threadIdx.x;
    const int w = t >> 6, lane = t & 63, quad = lane >> 4, c16 = lane & 15;
    const int n0 = blockIdx.x * 16;
    const int nvalid = min(16, N - n0);

    if (t < NGRAPH) { gs1[t] = 0.f; gs2[t] = 0.f; gv2[t] = 0.f; }
    if (t < 16) {
        spec_l[t] = (t < nvalid) ? species[n0 + t] : -1;
        bat_l[t]  = (t < nvalid) ? batch[n0 + t] : 0;
    }
    for (int i = t; i < 2048; i += 256) {
        int n = i >> 7, col = i & 127;
        float hv = 0.f, uv = 0.f;
        if (n < nvalid) {
            hv = hidden_b[(size_t)(n0 + n) * 128 + col];
            uv = up[(size_t)(n0 + n) * 128 + col];
        }
        if (col < 32) {
            sh_bf[n * 40 + col] = f2bf(hv); su_bf[n * 40 + col] = f2bf(uv);
            suT[col * 16 + n] = uv;
        } else {
            int idx = col - 32, c = idx % 3, a = idx / 3;
            vh_bf[(c * 16 + n) * 40 + a] = f2bf(hv);
            vu_bf[(c * 16 + n) * 40 + a] = f2bf(uv);
            vhT[(c * 32 + a) * 16 + n] = hv;
            vuT[(c * 32 + a) * 16 + n] = uv;
        }
    }
    __syncthreads();

    const v4f z4 = {0.f, 0.f, 0.f, 0.f};
    v4f o0[2];                    // [zh] -> out0[node=quad*4+r][z=zh*16+c16]
    v4f o1[3][2];                 // [c][zh]
    o0[0] = z4; o0[1] = z4;
#pragma unroll
    for (int c = 0; c < 3; ++c) { o1[c][0] = z4; o1[c][1] = z4; }

    v8bf a_sh = frag16(sh_bf + c16 * 40 + quad * 8);
    v8bf a_su = frag16(su_bf + c16 * 40 + quad * 8);
    const u16* pkw = pk + (w * 256 + c16) * 32 + quad * 8;

    // 16 named fragment loads for one path section (64 VGPRs, all in flight)
#define L16(POFF) \
    v8bf q0  = frag16(pkw + (POFF) + 0 * 512),  q1  = frag16(pkw + (POFF) + 1 * 512), \
         q2  = frag16(pkw + (POFF) + 2 * 512),  q3  = frag16(pkw + (POFF) + 3 * 512), \
         q4  = frag16(pkw + (POFF) + 4 * 512),  q5  = frag16(pkw + (POFF) + 5 * 512), \
         q6  = frag16(pkw + (POFF) + 6 * 512),  q7  = frag16(pkw + (POFF) + 7 * 512), \
         q8  = frag16(pkw + (POFF) + 8 * 512),  q9  = frag16(pkw + (POFF) + 9 * 512), \
         q10 = frag16(pkw + (POFF) + 10 * 512), q11 = frag16(pkw + (POFF) + 11 * 512), \
         q12 = frag16(pkw + (POFF) + 12 * 512), q13 = frag16(pkw + (POFF) + 13 * 512), \
         q14 = frag16(pkw + (POFF) + 14 * 512), q15 = frag16(pkw + (POFF) + 15 * 512);

#define P000(Q0, Q1, J) { \
    v4f y = *(const v4f*)(suT + (w * 8 + (J)) * 16 + quad * 4); \
    v4f C0 = MFMA(a_sh, Q0, z4), C1 = MFMA(a_sh, Q1, z4); \
    _Pragma("unroll") for (int r = 0; r < 4; ++r) { \
        o0[0][r] += C0[r] * y[r]; o0[1][r] += C1[r] * y[r]; } }

#define P011(Q0, Q1, J) { \
    v4f C0 = MFMA(a_sh, Q0, z4), C1 = MFMA(a_sh, Q1, z4); \
    _Pragma("unroll") for (int c = 0; c < 3; ++c) { \
        v4f y = *(const v4f*)(vuT + (c * 32 + w * 8 + (J)) * 16 + quad * 4); \
        _Pragma("unroll") for (int r = 0; r < 4; ++r) { \
            o1[c][0][r] += C0[r] * y[r]; o1[c][1][r] += C1[r] * y[r]; } } }

#define P101(Q0, Q1, J) { \
    v4f C0 = MFMA(a_su, Q0, z4), C1 = MFMA(a_su, Q1, z4); \
    _Pragma("unroll") for (int c = 0; c < 3; ++c) { \
        v4f y = *(const v4f*)(vhT + (c * 32 + w * 8 + (J)) * 16 + quad * 4); \
        _Pragma("unroll") for (int r = 0; r < 4; ++r) { \
            o1[c][0][r] += C0[r] * y[r]; o1[c][1][r] += C1[r] * y[r]; } } }

#define P110(Q0, Q1, J) { \
    _Pragma("unroll") for (int c = 0; c < 3; ++c) { \
        v4f y = *(const v4f*)(vhT + (c * 32 + w * 8 + (J)) * 16 + quad * 4); \
        v4f C0 = MFMA(a_vu0c[c], Q0, z4), C1 = MFMA(a_vu0c[c], Q1, z4); \
        _Pragma("unroll") for (int r = 0; r < 4; ++r) { \
            o0[0][r] += C0[r] * y[r]; o0[1][r] += C1[r] * y[r]; } } }

#define SEC(PX) PX(q0,q1,0) PX(q2,q3,1) PX(q4,q5,2) PX(q6,q7,3) \
                PX(q8,q9,4) PX(q10,q11,5) PX(q12,q13,6) PX(q14,q15,7)

    { L16(OFF_000) SEC(P000) }
    { L16(OFF_011) SEC(P011) }
    { L16(OFF_101) SEC(P101) }
    v8bf a_vu0 = frag16(vu_bf + (0 * 16 + c16) * 40 + quad * 8);
    v8bf a_vu1 = frag16(vu_bf + (1 * 16 + c16) * 40 + quad * 8);
    v8bf a_vu2 = frag16(vu_bf + (2 * 16 + c16) * 40 + quad * 8);
    const v8bf a_vu0c[3] = {a_vu0, a_vu1, a_vu2};
    { L16(OFF_110) SEC(P110) }

#undef L16
#undef P000
#undef P011
#undef P101
#undef P110
#undef SEC

    // ---- self connection: species-masked A-frags, species split over waves ----
    {
        const int s0 = (w < 2) ? w * 3 : 6 + (w - 2) * 2;
        const int ns = (w < 2) ? 3 : 2;
        v8bf zf = __builtin_bit_cast(v8bf, (v4u_t){0u, 0u, 0u, 0u});
        int sp = spec_l[c16];
        v8bf a_vh0 = frag16(vh_bf + (0 * 16 + c16) * 40 + quad * 8);
        v8bf a_vh1 = frag16(vh_bf + (1 * 16 + c16) * 40 + quad * 8);
        v8bf a_vh2 = frag16(vh_bf + (2 * 16 + c16) * 40 + quad * 8);
        for (int si = s0; si < s0 + ns; ++si) {
            bool m = (sp == si);
            v8bf ash_m = m ? a_sh : zf;
            v8bf am0 = m ? a_vh0 : zf;
            v8bf am1 = m ? a_vh1 : zf;
            v8bf am2 = m ? a_vh2 : zf;
#pragma unroll
            for (int zh = 0; zh < 2; ++zh) {
                int boff = (si * 32 + zh * 16 + c16) * 32 + quad * 8;
                v8bf bf0 = frag16(pk + OFF_SC0 + boff);
                v8bf bf1 = frag16(pk + OFF_SC1 + boff);
                o0[zh] = MFMA(ash_m, bf0, o0[zh]);
                o1[0][zh] = MFMA(am0, bf1, o1[0][zh]);
                o1[1][zh] = MFMA(am1, bf1, o1[1][zh]);
                o1[2][zh] = MFMA(am2, bf1, o1[2][zh]);
            }
        }
    }

    // ---- epilogue: cross-wave reduce through red (overlays staging) ----
    __syncthreads();
#pragma unroll
    for (int r = 0; r < 4; ++r) {
        int n = quad * 4 + r;
        float* row = red + (w * 16 + n) * 132;
        row[c16]      = o0[0][r];
        row[16 + c16] = o0[1][r];
#pragma unroll
        for (int c = 0; c < 3; ++c) {
            row[32 + c16 * 3 + c]        = o1[c][0][r];
            row[32 + (16 + c16) * 3 + c] = o1[c][1][r];
        }
    }
    __syncthreads();
    {
        int n = t >> 4, seg = t & 15;
        v4f sa = z4, sb = z4;
#pragma unroll
        for (int ww = 0; ww < 4; ++ww) {
            const float* rp = red + (ww * 16 + n) * 132 + seg * 8;
            sa += *(const v4f*)rp;
            sb += *(const v4f*)(rp + 4);
        }
        float s1p = 0.f, s2p = 0.f, v2p = 0.f;
        if (seg < 4) {
            sa += *(const v4f*)(lp_b0 + seg * 8);
            sb += *(const v4f*)(lp_b0 + seg * 8 + 4);
            s1p = sa[0] + sa[1] + sa[2] + sa[3] + sb[0] + sb[1] + sb[2] + sb[3];
            s2p = sa[0]*sa[0] + sa[1]*sa[1] + sa[2]*sa[2] + sa[3]*sa[3]
                + sb[0]*sb[0] + sb[1]*sb[1] + sb[2]*sb[2] + sb[3]*sb[3];
        } else {
            v2p = sa[0]*sa[0] + sa[1]*sa[1] + sa[2]*sa[2] + sa[3]*sa[3]
                + sb[0]*sb[0] + sb[1]*sb[1] + sb[2]*sb[2] + sb[3]*sb[3];
        }
        if (n < nvalid) {
            float* op = zout + (size_t)(n0 + n) * 128 + seg * 8;
            *(v4f*)op = sa;
            *(v4f*)(op + 4) = sb;
        }
#pragma unroll
        for (int off = 8; off >= 1; off >>= 1) {
            s1p += __shfl_xor(s1p, off, 16);
            s2p += __shfl_xor(s2p, off, 16);
            v2p += __shfl_xor(v2p, off, 16);
        }
        if (seg == 0 && n < nvalid) {
            int g = bat_l[n];
            atomicAdd(&gs1[g], s1p);
            atomicAdd(&gs2[g], s2p);
            atomicAdd(&gv2[g], v2p);
        }
    }
    __syncthreads();
    {
        const int bank = blockIdx.x & (NBANK - 1);
        if (t < NGRAPH) {
            if (gs1[t] != 0.f) atomicAdd(&S1b[bank * NGRAPH + t], gs1[t]);
            if (gs2[t] != 0.f) atomicAdd(&S2b[bank * NGRAPH + t], gs2[t]);
            if (gv2[t] != 0.f) atomicAdd(&V2b[bank * NGRAPH + t], gv2[t]);
        }
    }
}

// ---------------------------------------------------------------------------
// LayerNorm + skip kernel (in-place on z written by tp_kernel).
// Prologue reduces the replicated stat banks in-WG (L2-resident reads).
// ---------------------------------------------------------------------------
__global__ __launch_bounds__(256)
void norm_kernel(const float* __restrict__ hidden_b, float* __restrict__ out_b,
                 const float* __restrict__ skw0, const float* __restrict__ skb0,
                 const float* __restrict__ skw1,
                 const float* __restrict__ lnw0, const float* __restrict__ lnb0,
                 const float* __restrict__ lnw1,
                 const int* __restrict__ batch,
                 const float* __restrict__ S1b, const float* __restrict__ S2b,
                 const float* __restrict__ V2b, const float* __restrict__ cntb, int N) {
    __shared__ __align__(16) float sh_l[8][32];
    __shared__ __align__(16) float vh_l[8][96];
    __shared__ float stat_s[3][NGRAPH];
    __shared__ float cnt_s[NGRAPH];
    const int t = threadIdx.x, z = t & 31, nl = t >> 5;
    const int n0 = blockIdx.x * 8;
    for (int i = t; i < 8 * 128; i += 256) {
        int n = i >> 7, col = i & 127;
        float v = (n0 + n < N) ? hidden_b[(size_t)(n0 + n) * 128 + col] : 0.f;
        if (col < 32) sh_l[n][col] = v; else vh_l[n][col - 32] = v;
    }
    if (t < 48) {
        int arr = t >> 4, g = t & 15;
        const float* base = (arr == 0) ? S1b : (arr == 1) ? S2b : V2b;
        float s = 0.f;
        for (int k = 0; k < NBANK; ++k) s += base[k * NGRAPH + g];
        stat_s[arr][g] = s;
    } else if (t < 64) {
        int g = t - 48;
        float c = 0.f;
        for (int k = 0; k < NCBANK; ++k) c += cntb[k * NGRAPH + g];
        cnt_s[g] = c;
    }
    __syncthreads();
    const int n = n0 + nl;
    if (n >= N) return;

    float sk0 = 0.f, s1 = 0.f, s2 = 0.f, s3 = 0.f;
    for (int a = 0; a < 32; ++a) {
        float w0 = skw0[a * 32 + z];
        float w1 = skw1[a * 32 + z];
        sk0 += sh_l[nl][a] * w0;
        s1 += vh_l[nl][a * 3 + 0] * w1;
        s2 += vh_l[nl][a * 3 + 1] * w1;
        s3 += vh_l[nl][a * 3 + 2] * w1;
    }
    int g = batch[n];
    float cM = fmaxf(cnt_s[g], 1.0f) * 32.0f;
    float mean = stat_s[0][g] / cM;
    float var = fmaxf(stat_s[1][g] / cM - mean * mean, 0.0f);
    float rs = rsqrtf(var + 1e-5f);
    float rv = rsqrtf(fmaxf(stat_s[2][g] / cM, 0.0f) + 1e-5f);

    size_t base = (size_t)n * 128;
    float z0 = out_b[base + z];
    out_b[base + z] = (z0 - mean) * rs * lnw0[z] + lnb0[z] + sk0 * INV32S + skb0[z];
    float lw = lnw1[z] * rv;
    float x0 = out_b[base + 32 + z * 3 + 0];
    float x1 = out_b[base + 32 + z * 3 + 1];
    float x2 = out_b[base + 32 + z * 3 + 2];
    out_b[base + 32 + z * 3 + 0] = x0 * lw + s1 * INV32S;
    out_b[base + 32 + z * 3 + 1] = x1 * lw + s2 * INV32S;
    out_b[base + 32 + z * 3 + 2] = x2 * lw + s3 * INV32S;
}

// ---------------------------------------------------------------------------
// Workspace layout (total = 2 MiB + 25.6 KiB for B=2):
//   tmp1  [0,       1 MiB)  : stageA out; REUSED as Weff (stageC out)
//   tmp2  [1 MiB,   2 MiB)  : stageB out; REUSED as bf16 packs (pack out)
//   cntb  [2 MiB, +1 KiB)   : cnt banks [NCBANK][16]
//   S1b/S2b/V2b             : stat banks [B][NBANK][16] each
// ---------------------------------------------------------------------------
extern "C" void kernel_launch(void* const* d_in, const int* in_sizes, int n_in,
                              void* d_out, int out_size, void* d_ws, size_t ws_size,
                              hipStream_t stream) {
    const float* hidden = (const float*)d_in[0];
    const float* up0    = (const float*)d_in[1];
    const float* hl_w0  = (const float*)d_in[2];
    const float* hl_w1  = (const float*)d_in[3];
    const float* ul_w0  = (const float*)d_in[4];
    const float* ul_w1  = (const float*)d_in[5];
    const float* w000   = (const float*)d_in[6];
    const float* w110   = (const float*)d_in[7];
    const float* w011   = (const float*)d_in[8];
    const float* w101   = (const float*)d_in[9];
    const float* lp_w0  = (const float*)d_in[10];
    const float* lp_b0  = (const float*)d_in[11];
    const float* lp_w1  = (const float*)d_in[12];
    const float* sc_w0  = (const float*)d_in[13];
    const float* sc_w1  = (const float*)d_in[14];
    const float* ln_w0  = (const float*)d_in[15];
    const float* ln_b0  = (const float*)d_in[16];
    const float* ln_w1  = (const float*)d_in[17];
    const float* sk_w0  = (const float*)d_in[18];
    const float* sk_b0  = (const float*)d_in[19];
    const float* sk_w1  = (const float*)d_in[20];
    const int* species  = (const int*)d_in[21];
    const int* batch    = (const int*)d_in[22];
    float* out = (float*)d_out;

    const int N = in_sizes[21];
    const int B = in_sizes[0] / (N * 128);

    float* ws = (float*)d_ws;
    float* tmp1 = ws;                                  // stageA out -> Weff
    float* tmp2 = tmp1 + (size_t)B * 4 * 32768;        // stageB out -> packs
    float* cntb = tmp2 + (size_t)B * 4 * 32768;        // [NCBANK][16]
    float* S1b = cntb + NCBANK * NGRAPH;               // [B][NBANK][16]
    float* S2b = S1b + (size_t)B * NBANK * NGRAPH;
    float* V2b = S2b + (size_t)B * NBANK * NGRAPH;
    int statn = NCBANK * NGRAPH + 3 * B * NBANK * NGRAPH;

    zero_kernel<<<(statn + 255) / 256, 256, 0, stream>>>(cntb, statn);
    count_kernel<<<(N + 255) / 256, 256, 0, stream>>>(batch, cntb, N);

    int nb = B * 4 * 32768 / 256;
    stageA_kernel<<<nb, 256, 0, stream>>>(w000, w110, w011, w101, lp_w0, lp_w1, tmp1);
    stageB_kernel<<<nb, 256, 0, stream>>>(ul_w0, ul_w1, tmp1, tmp2);
    stageC_kernel<<<nb, 256, 0, stream>>>(hl_w0, hl_w1, tmp2, tmp1);   // Weff -> tmp1

    u16* packs = (u16*)tmp2;                           // tmp2 dead after stageC
    int ptotal = B * 151552;
    pack_kernel<<<(ptotal + 255) / 256, 256, 0, stream>>>(tmp1, sc_w0, sc_w1, packs, ptotal);

    for (int b = 0; b < B; ++b) {
        const float* up = (b == 0) ? up0 : out + (size_t)(b - 1) * N * 128;
        const u16* pb = packs + (size_t)b * 151552;
        tp_kernel<<<(N + 15) / 16, 256, 0, stream>>>(
            hidden + (size_t)b * N * 128, up, pb,
            lp_b0 + b * MULT, species, batch,
            S1b + (size_t)b * NBANK * NGRAPH, S2b + (size_t)b * NBANK * NGRAPH,
            V2b + (size_t)b * NBANK * NGRAPH,
            out + (size_t)b * N * 128, N);
        norm_kernel<<<(N + 7) / 8, 256, 0, stream>>>(
            hidden + (size_t)b * N * 128, out + (size_t)b * N * 128,
            sk_w0 + b * 1024, sk_b0 + b * MULT, sk_w1 + b * 1024,
            ln_w0 + b * MULT, ln_b0 + b * MULT, ln_w1 + b * MULT,
            batch, S1b + (size_t)b * NBANK * NGRAPH, S2b + (size_t)b * NBANK * NGRAPH,
            V2b + (size_t)b * NBANK * NGRAPH, cntb, N);
    }
}

// Round 6
// 1238.323 us; speedup vs baseline: 1.4250x; 1.4250x over previous
//
#include <hip/hip_runtime.h>
#include <math.h>

#define MULT 32
#define NSPEC 10
#define NGRAPH 16
#define NBANK 64          /* stat replication banks (tp_kernel) */
#define NCBANK 16         /* cnt replication banks (count_kernel) */
#define INV_SC 0.05590169943749474f   /* 1/sqrt(32*10) */
#define INV32S 0.17677669529663687f   /* 1/sqrt(32) */

typedef unsigned short u16;
typedef __bf16 v8bf __attribute__((ext_vector_type(8)));
typedef float v4f __attribute__((ext_vector_type(4)));
typedef unsigned int v4u_t __attribute__((ext_vector_type(4)));

__device__ __forceinline__ u16 f2bf(float f) {
    unsigned int u = __builtin_bit_cast(unsigned int, f);
    unsigned int r = u + 0x7fffu + ((u >> 16) & 1u);
    return (u16)(r >> 16);
}

__device__ __forceinline__ v8bf frag16(const u16* p) {
    return __builtin_bit_cast(v8bf, *(const v4u_t*)p);
}

#define MFMA(a, b, c) __builtin_amdgcn_mfma_f32_16x16x32_bf16(a, b, c, 0, 0, 0)

#define GLL(g, l) __builtin_amdgcn_global_load_lds( \
    (const __attribute__((address_space(1))) unsigned int*)(g), \
    (__attribute__((address_space(3))) unsigned int*)(l), 16, 0, 0)

// ---------------------------------------------------------------------------
// small utility kernels
// ---------------------------------------------------------------------------
__global__ void zero_kernel(float* __restrict__ p, int n) {
    int i = blockIdx.x * 256 + threadIdx.x;
    if (i < n) p[i] = 0.0f;
}

__global__ void count_kernel(const int* __restrict__ batch, float* __restrict__ cntb, int N) {
    __shared__ int bins[NGRAPH];
    int t = threadIdx.x;
    if (t < NGRAPH) bins[t] = 0;
    __syncthreads();
    int i = blockIdx.x * 256 + t;
    if (i < N) atomicAdd(&bins[batch[i]], 1);
    __syncthreads();
    int bank = blockIdx.x & (NCBANK - 1);
    if (t < NGRAPH && bins[t] > 0) atomicAdd(&cntb[bank * NGRAPH + t], (float)bins[t]);
}

// ---------------------------------------------------------------------------
// effective-weight precompute (fp32):
//  Weff[path,b][a,bb,z], path: 0=000, 1=110, 2=011, 3=101
// ---------------------------------------------------------------------------
__global__ void stageA_kernel(const float* __restrict__ w000, const float* __restrict__ w110,
                              const float* __restrict__ w011, const float* __restrict__ w101,
                              const float* __restrict__ lp0, const float* __restrict__ lp1,
                              float* __restrict__ tmp1) {
    int gid = blockIdx.x * 256 + threadIdx.x;
    int tslot = gid >> 15;
    int e = gid & 32767;
    int z = e & 31;
    int uv = e >> 5;
    int b = tslot >> 2, path = tslot & 3;
    const float* W = (path == 0 ? w000 : path == 1 ? w110 : path == 2 ? w011 : w101) + b * 32768;
    const float* L = ((path == 0 || path == 1) ? lp0 : lp1) + b * 1024;
    float scale = (path == 1) ? (1.0f / (8192.0f * 1.7320508075688772f)) : (1.0f / 8192.0f);
    const float* wr = W + uv * 32;
    float acc = 0.0f;
    for (int w = 0; w < 32; ++w) acc += wr[w] * L[w * 32 + z];
    tmp1[gid] = acc * scale;
}

__global__ void stageB_kernel(const float* __restrict__ ul0, const float* __restrict__ ul1,
                              const float* __restrict__ tmp1, float* __restrict__ tmp2) {
    int gid = blockIdx.x * 256 + threadIdx.x;
    int tslot = gid >> 15;
    int e = gid & 32767;
    int z = e & 31;
    int bb = (e >> 5) & 31;
    int u = e >> 10;
    int b = tslot >> 2, path = tslot & 3;
    const float* U = ((path == 0 || path == 3) ? ul0 : ul1) + b * 1024;
    const float* in = tmp1 + (size_t)tslot * 32768 + u * 1024 + z;
    float acc = 0.0f;
    for (int v = 0; v < 32; ++v) acc += U[bb * 32 + v] * in[v * 32];
    tmp2[gid] = acc;
}

__global__ void stageC_kernel(const float* __restrict__ hl0, const float* __restrict__ hl1,
                              const float* __restrict__ tmp2, float* __restrict__ Weff) {
    int gid = blockIdx.x * 256 + threadIdx.x;
    int tslot = gid >> 15;
    int e = gid & 32767;
    int z = e & 31;
    int bb = (e >> 5) & 31;
    int a = e >> 10;
    int b = tslot >> 2, path = tslot & 3;
    const float* H = ((path == 0 || path == 2) ? hl0 : hl1) + b * 1024;
    const float* in = tmp2 + (size_t)tslot * 32768 + bb * 32 + z;
    float acc = 0.0f;
    for (int u = 0; u < 32; ++u) acc += H[a * 32 + u] * in[u * 1024];
    Weff[gid] = acc;
}

// ---------------------------------------------------------------------------
// pack kernel: fp32 Weff / sc weights -> bf16, B-frag layouts (linear = col*32+k)
// per-b flat layout (151552 u16):
//  [0,32768):        W000T col=bb*32+z, k=a
//  [32768,65536):    W011T col=bb*32+z, k=a
//  [65536,98304):    W101T col=a*32+z,  k=bb
//  [98304,131072):   W110X col=a*32+z,  k=bb
//  [131072,141312):  WSC0P [s][col=z][k=a]  (x INV_SC)
//  [141312,151552):  WSC1P [s][col=z][k=a]  (x INV_SC)
// ---------------------------------------------------------------------------
__global__ void pack_kernel(const float* __restrict__ Weff,
                            const float* __restrict__ sc_w0, const float* __restrict__ sc_w1,
                            u16* __restrict__ packs, int total) {
    int gid = blockIdx.x * 256 + threadIdx.x;
    if (gid >= total) return;
    int b = gid / 151552;
    int e = gid - b * 151552;
    float v;
    if (e < 131072) {
        int which = e >> 15;          // 0:000 1:011 2:101 3:110
        int e2 = e & 32767;
        int k = e2 & 31;
        int z = (e2 >> 5) & 31;
        int hi = e2 >> 10;
        int path = (which == 0) ? 0 : (which == 1) ? 2 : (which == 2) ? 3 : 1;
        int a  = (which < 2) ? k  : hi;
        int bb = (which < 2) ? hi : k;
        v = Weff[(size_t)((b * 4 + path) * 32 + a) * 1024 + bb * 32 + z];
    } else {
        int e2 = e - 131072;
        int which = e2 / 10240;
        int e3 = e2 - which * 10240;
        int s = e3 >> 10, z = (e3 >> 5) & 31, a = e3 & 31;
        const float* S = which ? sc_w1 : sc_w0;
        v = S[(size_t)b * 10240 + a * 320 + s * 32 + z] * INV_SC;
    }
    packs[gid] = f2bf(v);
}

// ---------------------------------------------------------------------------
// MFMA TP + self-connection + stats kernel.  One WG (4 waves) per 16 nodes.
// R2 structure; weight fragments now stream through a WAVE-PRIVATE 6-slot LDS
// ring fed by global_load_lds (2 frags = 2KB per chunk, 32 chunks/wave).
// Load depth lives in the vmcnt queue (10 loads in flight), not VGPRs, so the
// register allocator has nothing to spill.  Counted s_waitcnt vmcnt(8) per
// step (tail 6/4/2/0); no barriers in the loop (slices are wave-disjoint).
// ---------------------------------------------------------------------------
__global__ __launch_bounds__(256)
void tp_kernel(const float* __restrict__ hidden_b, const float* __restrict__ up,
               const u16* __restrict__ pk,
               const float* __restrict__ lp_b0,
               const int* __restrict__ species, const int* __restrict__ batch,
               float* __restrict__ S1b, float* __restrict__ S2b, float* __restrict__ V2b,
               float* __restrict__ zout, int N) {
    constexpr int OFF_000 = 0, OFF_011 = 32768, OFF_101 = 65536, OFF_110 = 98304;
    constexpr int OFF_SC0 = 131072, OFF_SC1 = 141312;

    // [0,24576): staging   [24576,73728): weight ring (overlaid by red after loop)
    __shared__ __align__(16) char smem[73728];
    __shared__ int spec_l[16];
    __shared__ int bat_l[16];
    __shared__ float gs1[NGRAPH], gs2[NGRAPH], gv2[NGRAPH];

    u16* sh_bf = (u16*)smem;                 // [16][40] bf16, A-layout
    u16* su_bf = (u16*)(smem + 1280);        // [16][40]
    u16* vu_bf = (u16*)(smem + 2560);        // [3][16][40]
    u16* vh_bf = (u16*)(smem + 6400);        // [3][16][40]
    float* suT = (float*)(smem + 10240);     // [32 bb][16 n] fp32 (Y)
    float* vuT = (float*)(smem + 12288);     // [3][32][16]
    float* vhT = (float*)(smem + 18432);     // [3][32][16]
    u16* wring = (u16*)(smem + 24576);       // [4 waves][6 slots][1024 u16]
    float* red = (float*)(smem + 24576);     // [4][16][132] fp32 (epilogue overlay)

    const int t = threadIdx.x;
    const int w = t >> 6, lane = t & 63, quad = lane >> 4, c16 = lane & 15;
    const int n0 = blockIdx.x * 16;
    const int nvalid = min(16, N - n0);

    const u16* pkw = pk + (w * 256 + c16) * 32 + quad * 8;   // per-lane W base
    u16* myring = wring + w * 6144;                          // wave-private ring

#define POFF(S) ((S) < 8 ? OFF_000 : (S) < 16 ? OFF_011 : (S) < 24 ? OFF_101 : OFF_110)
#define ISSUE(S) do { \
        const u16* g_ = pkw + POFF(S) + ((S) & 7) * 1024; \
        u16* l_ = myring + ((S) % 6) * 1024; \
        GLL(g_, l_); \
        GLL(g_ + 512, l_ + 512); \
    } while (0)

    // prologue: 5 chunks (10 loads) in flight; they land while staging runs
    ISSUE(0); ISSUE(1); ISSUE(2); ISSUE(3); ISSUE(4);

    if (t < NGRAPH) { gs1[t] = 0.f; gs2[t] = 0.f; gv2[t] = 0.f; }
    if (t < 16) {
        spec_l[t] = (t < nvalid) ? species[n0 + t] : -1;
        bat_l[t]  = (t < nvalid) ? batch[n0 + t] : 0;
    }
    for (int i = t; i < 2048; i += 256) {
        int n = i >> 7, col = i & 127;
        float hv = 0.f, uv = 0.f;
        if (n < nvalid) {
            hv = hidden_b[(size_t)(n0 + n) * 128 + col];
            uv = up[(size_t)(n0 + n) * 128 + col];
        }
        if (col < 32) {
            sh_bf[n * 40 + col] = f2bf(hv); su_bf[n * 40 + col] = f2bf(uv);
            suT[col * 16 + n] = uv;
        } else {
            int idx = col - 32, c = idx % 3, a = idx / 3;
            vh_bf[(c * 16 + n) * 40 + a] = f2bf(hv);
            vu_bf[(c * 16 + n) * 40 + a] = f2bf(uv);
            vhT[(c * 32 + a) * 16 + n] = hv;
            vuT[(c * 32 + a) * 16 + n] = uv;
        }
    }
    __syncthreads();

    const v4f z4 = {0.f, 0.f, 0.f, 0.f};
    v4f o0[2];                    // [zh] -> out0[node=quad*4+r][z=zh*16+c16]
    v4f o1[3][2];                 // [c][zh]
    o0[0] = z4; o0[1] = z4;
#pragma unroll
    for (int c = 0; c < 3; ++c) { o1[c][0] = z4; o1[c][1] = z4; }

    v8bf a_sh = frag16(sh_bf + c16 * 40 + quad * 8);
    v8bf a_su = frag16(su_bf + c16 * 40 + quad * 8);

#define B000 { \
    v4f y = *(const v4f*)(suT + hi * 16 + quad * 4); \
    v4f C0 = MFMA(a_sh, wf0, z4), C1 = MFMA(a_sh, wf1, z4); \
    _Pragma("unroll") for (int r = 0; r < 4; ++r) { \
        o0[0][r] += C0[r] * y[r]; o0[1][r] += C1[r] * y[r]; } }

#define B011 { \
    v4f C0 = MFMA(a_sh, wf0, z4), C1 = MFMA(a_sh, wf1, z4); \
    _Pragma("unroll") for (int c = 0; c < 3; ++c) { \
        v4f y = *(const v4f*)(vuT + (c * 32 + hi) * 16 + quad * 4); \
        _Pragma("unroll") for (int r = 0; r < 4; ++r) { \
            o1[c][0][r] += C0[r] * y[r]; o1[c][1][r] += C1[r] * y[r]; } } }

#define B101 { \
    v4f C0 = MFMA(a_su, wf0, z4), C1 = MFMA(a_su, wf1, z4); \
    _Pragma("unroll") for (int c = 0; c < 3; ++c) { \
        v4f y = *(const v4f*)(vhT + (c * 32 + hi) * 16 + quad * 4); \
        _Pragma("unroll") for (int r = 0; r < 4; ++r) { \
            o1[c][0][r] += C0[r] * y[r]; o1[c][1][r] += C1[r] * y[r]; } } }

#define B110 { \
    v4f y0 = *(const v4f*)(vhT + (0 * 32 + hi) * 16 + quad * 4); \
    v4f y1 = *(const v4f*)(vhT + (1 * 32 + hi) * 16 + quad * 4); \
    v4f y2 = *(const v4f*)(vhT + (2 * 32 + hi) * 16 + quad * 4); \
    v4f C00 = MFMA(a_vu0, wf0, z4), C01 = MFMA(a_vu0, wf1, z4); \
    v4f C10 = MFMA(a_vu1, wf0, z4), C11 = MFMA(a_vu1, wf1, z4); \
    v4f C20 = MFMA(a_vu2, wf0, z4), C21 = MFMA(a_vu2, wf1, z4); \
    _Pragma("unroll") for (int r = 0; r < 4; ++r) { \
        o0[0][r] += C00[r]*y0[r] + C10[r]*y1[r] + C20[r]*y2[r]; \
        o0[1][r] += C01[r]*y0[r] + C11[r]*y1[r] + C21[r]*y2[r]; } }

    // STEP(S): wait chunk S's 2 loads (oldest); consume; issue chunk S+5.
    // N = min(8, 2*(31-S)): steady 8, tail 6/4/2/0.
#define STEP(S, NW, BODYM) { \
    asm volatile("s_waitcnt vmcnt(" #NW ")" ::: "memory"); \
    { \
        const int hi = w * 8 + ((S) & 7); \
        v8bf wf0 = frag16(myring + ((S) % 6) * 1024 + lane * 8); \
        v8bf wf1 = frag16(myring + ((S) % 6) * 1024 + 512 + lane * 8); \
        BODYM \
    } \
    if ((S) + 5 <= 31) { ISSUE((S) + 5); } }

    STEP(0, 8, B000)  STEP(1, 8, B000)  STEP(2, 8, B000)  STEP(3, 8, B000)
    STEP(4, 8, B000)  STEP(5, 8, B000)  STEP(6, 8, B000)  STEP(7, 8, B000)
    STEP(8, 8, B011)  STEP(9, 8, B011)  STEP(10, 8, B011) STEP(11, 8, B011)
    STEP(12, 8, B011) STEP(13, 8, B011) STEP(14, 8, B011) STEP(15, 8, B011)
    STEP(16, 8, B101) STEP(17, 8, B101) STEP(18, 8, B101) STEP(19, 8, B101)
    STEP(20, 8, B101) STEP(21, 8, B101) STEP(22, 8, B101) STEP(23, 8, B101)
    v8bf a_vu0 = frag16(vu_bf + (0 * 16 + c16) * 40 + quad * 8);
    v8bf a_vu1 = frag16(vu_bf + (1 * 16 + c16) * 40 + quad * 8);
    v8bf a_vu2 = frag16(vu_bf + (2 * 16 + c16) * 40 + quad * 8);
    STEP(24, 8, B110) STEP(25, 8, B110) STEP(26, 8, B110) STEP(27, 8, B110)
    STEP(28, 6, B110) STEP(29, 4, B110) STEP(30, 2, B110) STEP(31, 0, B110)

#undef STEP
#undef B000
#undef B011
#undef B101
#undef B110
#undef ISSUE
#undef POFF

    // ---- self connection: species-masked A-frags, species split over waves ----
    {
        const int s0 = (w < 2) ? w * 3 : 6 + (w - 2) * 2;
        const int ns = (w < 2) ? 3 : 2;
        v8bf zf = __builtin_bit_cast(v8bf, (v4u_t){0u, 0u, 0u, 0u});
        int sp = spec_l[c16];
        v8bf a_vh0 = frag16(vh_bf + (0 * 16 + c16) * 40 + quad * 8);
        v8bf a_vh1 = frag16(vh_bf + (1 * 16 + c16) * 40 + quad * 8);
        v8bf a_vh2 = frag16(vh_bf + (2 * 16 + c16) * 40 + quad * 8);
        for (int si = s0; si < s0 + ns; ++si) {
            bool m = (sp == si);
            v8bf ash_m = m ? a_sh : zf;
            v8bf am0 = m ? a_vh0 : zf;
            v8bf am1 = m ? a_vh1 : zf;
            v8bf am2 = m ? a_vh2 : zf;
#pragma unroll
            for (int zh = 0; zh < 2; ++zh) {
                int boff = (si * 32 + zh * 16 + c16) * 32 + quad * 8;
                v8bf bf0 = frag16(pk + OFF_SC0 + boff);
                v8bf bf1 = frag16(pk + OFF_SC1 + boff);
                o0[zh] = MFMA(ash_m, bf0, o0[zh]);
                o1[0][zh] = MFMA(am0, bf1, o1[0][zh]);
                o1[1][zh] = MFMA(am1, bf1, o1[1][zh]);
                o1[2][zh] = MFMA(am2, bf1, o1[2][zh]);
            }
        }
    }

    // ---- epilogue: cross-wave reduce through red (overlays the ring) ----
    __syncthreads();
#pragma unroll
    for (int r = 0; r < 4; ++r) {
        int n = quad * 4 + r;
        float* row = red + (w * 16 + n) * 132;
        row[c16]      = o0[0][r];
        row[16 + c16] = o0[1][r];
#pragma unroll
        for (int c = 0; c < 3; ++c) {
            row[32 + c16 * 3 + c]        = o1[c][0][r];
            row[32 + (16 + c16) * 3 + c] = o1[c][1][r];
        }
    }
    __syncthreads();
    {
        int n = t >> 4, seg = t & 15;
        v4f sa = z4, sb = z4;
#pragma unroll
        for (int ww = 0; ww < 4; ++ww) {
            const float* rp = red + (ww * 16 + n) * 132 + seg * 8;
            sa += *(const v4f*)rp;
            sb += *(const v4f*)(rp + 4);
        }
        float s1p = 0.f, s2p = 0.f, v2p = 0.f;
        if (seg < 4) {
            sa += *(const v4f*)(lp_b0 + seg * 8);
            sb += *(const v4f*)(lp_b0 + seg * 8 + 4);
            s1p = sa[0] + sa[1] + sa[2] + sa[3] + sb[0] + sb[1] + sb[2] + sb[3];
            s2p = sa[0]*sa[0] + sa[1]*sa[1] + sa[2]*sa[2] + sa[3]*sa[3]
                + sb[0]*sb[0] + sb[1]*sb[1] + sb[2]*sb[2] + sb[3]*sb[3];
        } else {
            v2p = sa[0]*sa[0] + sa[1]*sa[1] + sa[2]*sa[2] + sa[3]*sa[3]
                + sb[0]*sb[0] + sb[1]*sb[1] + sb[2]*sb[2] + sb[3]*sb[3];
        }
        if (n < nvalid) {
            float* op = zout + (size_t)(n0 + n) * 128 + seg * 8;
            *(v4f*)op = sa;
            *(v4f*)(op + 4) = sb;
        }
#pragma unroll
        for (int off = 8; off >= 1; off >>= 1) {
            s1p += __shfl_xor(s1p, off, 16);
            s2p += __shfl_xor(s2p, off, 16);
            v2p += __shfl_xor(v2p, off, 16);
        }
        if (seg == 0 && n < nvalid) {
            int g = bat_l[n];
            atomicAdd(&gs1[g], s1p);
            atomicAdd(&gs2[g], s2p);
            atomicAdd(&gv2[g], v2p);
        }
    }
    __syncthreads();
    {
        const int bank = blockIdx.x & (NBANK - 1);
        if (t < NGRAPH) {
            if (gs1[t] != 0.f) atomicAdd(&S1b[bank * NGRAPH + t], gs1[t]);
            if (gs2[t] != 0.f) atomicAdd(&S2b[bank * NGRAPH + t], gs2[t]);
            if (gv2[t] != 0.f) atomicAdd(&V2b[bank * NGRAPH + t], gv2[t]);
        }
    }
}

// ---------------------------------------------------------------------------
// LayerNorm + skip kernel (in-place on z written by tp_kernel).
// Prologue reduces the replicated stat banks in-WG (L2-resident reads).
// ---------------------------------------------------------------------------
__global__ __launch_bounds__(256)
void norm_kernel(const float* __restrict__ hidden_b, float* __restrict__ out_b,
                 const float* __restrict__ skw0, const float* __restrict__ skb0,
                 const float* __restrict__ skw1,
                 const float* __restrict__ lnw0, const float* __restrict__ lnb0,
                 const float* __restrict__ lnw1,
                 const int* __restrict__ batch,
                 const float* __restrict__ S1b, const float* __restrict__ S2b,
                 const float* __restrict__ V2b, const float* __restrict__ cntb, int N) {
    __shared__ __align__(16) float sh_l[8][32];
    __shared__ __align__(16) float vh_l[8][96];
    __shared__ float stat_s[3][NGRAPH];
    __shared__ float cnt_s[NGRAPH];
    const int t = threadIdx.x, z = t & 31, nl = t >> 5;
    const int n0 = blockIdx.x * 8;
    for (int i = t; i < 8 * 128; i += 256) {
        int n = i >> 7, col = i & 127;
        float v = (n0 + n < N) ? hidden_b[(size_t)(n0 + n) * 128 + col] : 0.f;
        if (col < 32) sh_l[n][col] = v; else vh_l[n][col - 32] = v;
    }
    if (t < 48) {
        int arr = t >> 4, g = t & 15;
        const float* base = (arr == 0) ? S1b : (arr == 1) ? S2b : V2b;
        float s = 0.f;
        for (int k = 0; k < NBANK; ++k) s += base[k * NGRAPH + g];
        stat_s[arr][g] = s;
    } else if (t < 64) {
        int g = t - 48;
        float c = 0.f;
        for (int k = 0; k < NCBANK; ++k) c += cntb[k * NGRAPH + g];
        cnt_s[g] = c;
    }
    __syncthreads();
    const int n = n0 + nl;
    if (n >= N) return;

    float sk0 = 0.f, s1 = 0.f, s2 = 0.f, s3 = 0.f;
    for (int a = 0; a < 32; ++a) {
        float w0 = skw0[a * 32 + z];
        float w1 = skw1[a * 32 + z];
        sk0 += sh_l[nl][a] * w0;
        s1 += vh_l[nl][a * 3 + 0] * w1;
        s2 += vh_l[nl][a * 3 + 1] * w1;
        s3 += vh_l[nl][a * 3 + 2] * w1;
    }
    int g = batch[n];
    float cM = fmaxf(cnt_s[g], 1.0f) * 32.0f;
    float mean = stat_s[0][g] / cM;
    float var = fmaxf(stat_s[1][g] / cM - mean * mean, 0.0f);
    float rs = rsqrtf(var + 1e-5f);
    float rv = rsqrtf(fmaxf(stat_s[2][g] / cM, 0.0f) + 1e-5f);

    size_t base = (size_t)n * 128;
    float z0 = out_b[base + z];
    out_b[base + z] = (z0 - mean) * rs * lnw0[z] + lnb0[z] + sk0 * INV32S + skb0[z];
    float lw = lnw1[z] * rv;
    float x0 = out_b[base + 32 + z * 3 + 0];
    float x1 = out_b[base + 32 + z * 3 + 1];
    float x2 = out_b[base + 32 + z * 3 + 2];
    out_b[base + 32 + z * 3 + 0] = x0 * lw + s1 * INV32S;
    out_b[base + 32 + z * 3 + 1] = x1 * lw + s2 * INV32S;
    out_b[base + 32 + z * 3 + 2] = x2 * lw + s3 * INV32S;
}

// ---------------------------------------------------------------------------
// Workspace layout (total = 2 MiB + 25.6 KiB for B=2):
//   tmp1  [0,       1 MiB)  : stageA out; REUSED as Weff (stageC out)
//   tmp2  [1 MiB,   2 MiB)  : stageB out; REUSED as bf16 packs (pack out)
//   cntb  [2 MiB, +1 KiB)   : cnt banks [NCBANK][16]
//   S1b/S2b/V2b             : stat banks [B][NBANK][16] each
// ---------------------------------------------------------------------------
extern "C" void kernel_launch(void* const* d_in, const int* in_sizes, int n_in,
                              void* d_out, int out_size, void* d_ws, size_t ws_size,
                              hipStream_t stream) {
    const float* hidden = (const float*)d_in[0];
    const float* up0    = (const float*)d_in[1];
    const float* hl_w0  = (const float*)d_in[2];
    const float* hl_w1  = (const float*)d_in[3];
    const float* ul_w0  = (const float*)d_in[4];
    const float* ul_w1  = (const float*)d_in[5];
    const float* w000   = (const float*)d_in[6];
    const float* w110   = (const float*)d_in[7];
    const float* w011   = (const float*)d_in[8];
    const float* w101   = (const float*)d_in[9];
    const float* lp_w0  = (const float*)d_in[10];
    const float* lp_b0  = (const float*)d_in[11];
    const float* lp_w1  = (const float*)d_in[12];
    const float* sc_w0  = (const float*)d_in[13];
    const float* sc_w1  = (const float*)d_in[14];
    const float* ln_w0  = (const float*)d_in[15];
    const float* ln_b0  = (const float*)d_in[16];
    const float* ln_w1  = (const float*)d_in[17];
    const float* sk_w0  = (const float*)d_in[18];
    const float* sk_b0  = (const float*)d_in[19];
    const float* sk_w1  = (const float*)d_in[20];
    const int* species  = (const int*)d_in[21];
    const int* batch    = (const int*)d_in[22];
    float* out = (float*)d_out;

    const int N = in_sizes[21];
    const int B = in_sizes[0] / (N * 128);

    float* ws = (float*)d_ws;
    float* tmp1 = ws;                                  // stageA out -> Weff
    float* tmp2 = tmp1 + (size_t)B * 4 * 32768;        // stageB out -> packs
    float* cntb = tmp2 + (size_t)B * 4 * 32768;        // [NCBANK][16]
    float* S1b = cntb + NCBANK * NGRAPH;               // [B][NBANK][16]
    float* S2b = S1b + (size_t)B * NBANK * NGRAPH;
    float* V2b = S2b + (size_t)B * NBANK * NGRAPH;
    int statn = NCBANK * NGRAPH + 3 * B * NBANK * NGRAPH;

    zero_kernel<<<(statn + 255) / 256, 256, 0, stream>>>(cntb, statn);
    count_kernel<<<(N + 255) / 256, 256, 0, stream>>>(batch, cntb, N);

    int nb = B * 4 * 32768 / 256;
    stageA_kernel<<<nb, 256, 0, stream>>>(w000, w110, w011, w101, lp_w0, lp_w1, tmp1);
    stageB_kernel<<<nb, 256, 0, stream>>>(ul_w0, ul_w1, tmp1, tmp2);
    stageC_kernel<<<nb, 256, 0, stream>>>(hl_w0, hl_w1, tmp2, tmp1);   // Weff -> tmp1

    u16* packs = (u16*)tmp2;                           // tmp2 dead after stageC
    int ptotal = B * 151552;
    pack_kernel<<<(ptotal + 255) / 256, 256, 0, stream>>>(tmp1, sc_w0, sc_w1, packs, ptotal);

    for (int b = 0; b < B; ++b) {
        const float* up = (b == 0) ? up0 : out + (size_t)(b - 1) * N * 128;
        const u16* pb = packs + (size_t)b * 151552;
        tp_kernel<<<(N + 15) / 16, 256, 0, stream>>>(
            hidden + (size_t)b * N * 128, up, pb,
            lp_b0 + b * MULT, species, batch,
            S1b + (size_t)b * NBANK * NGRAPH, S2b + (size_t)b * NBANK * NGRAPH,
            V2b + (size_t)b * NBANK * NGRAPH,
            out + (size_t)b * N * 128, N);
        norm_kernel<<<(N + 7) / 8, 256, 0, stream>>>(
            hidden + (size_t)b * N * 128, out + (size_t)b * N * 128,
            sk_w0 + b * 1024, sk_b0 + b * MULT, sk_w1 + b * 1024,
            ln_w0 + b * MULT, ln_b0 + b * MULT, ln_w1 + b * MULT,
            batch, S1b + (size_t)b * NBANK * NGRAPH, S2b + (size_t)b * NBANK * NGRAPH,
            V2b + (size_t)b * NBANK * NGRAPH, cntb, N);
    }
}

// Round 7
// 385.192 us; speedup vs baseline: 4.5811x; 3.2148x over previous
//
#include <hip/hip_runtime.h>
#include <math.h>

#define MULT 32
#define NSPEC 10
#define NGRAPH 16
#define NBANK 64          /* stat replication banks (tp_kernel) */
#define NCBANK 16         /* cnt replication banks (count_kernel) */
#define INV_SC 0.05590169943749474f   /* 1/sqrt(32*10) */
#define INV32S 0.17677669529663687f   /* 1/sqrt(32) */

typedef unsigned short u16;
typedef __bf16 v8bf __attribute__((ext_vector_type(8)));
typedef float v4f __attribute__((ext_vector_type(4)));
typedef unsigned int v4u_t __attribute__((ext_vector_type(4)));

__device__ __forceinline__ u16 f2bf(float f) {
    unsigned int u = __builtin_bit_cast(unsigned int, f);
    unsigned int r = u + 0x7fffu + ((u >> 16) & 1u);
    return (u16)(r >> 16);
}

__device__ __forceinline__ v8bf frag16(const u16* p) {
    return __builtin_bit_cast(v8bf, *(const v4u_t*)p);
}

#define MFMA(a, b, c) __builtin_amdgcn_mfma_f32_16x16x32_bf16(a, b, c, 0, 0, 0)

// ---------------------------------------------------------------------------
// small utility kernels
// ---------------------------------------------------------------------------
__global__ void zero_kernel(float* __restrict__ p, int n) {
    int i = blockIdx.x * 256 + threadIdx.x;
    if (i < n) p[i] = 0.0f;
}

__global__ void count_kernel(const int* __restrict__ batch, float* __restrict__ cntb, int N) {
    __shared__ int bins[NGRAPH];
    int t = threadIdx.x;
    if (t < NGRAPH) bins[t] = 0;
    __syncthreads();
    int i = blockIdx.x * 256 + t;
    if (i < N) atomicAdd(&bins[batch[i]], 1);
    __syncthreads();
    int bank = blockIdx.x & (NCBANK - 1);
    if (t < NGRAPH && bins[t] > 0) atomicAdd(&cntb[bank * NGRAPH + t], (float)bins[t]);
}

// ---------------------------------------------------------------------------
// effective-weight precompute (fp32):
//  Weff[path,b][a,bb,z], path: 0=000, 1=110, 2=011, 3=101
// ---------------------------------------------------------------------------
__global__ void stageA_kernel(const float* __restrict__ w000, const float* __restrict__ w110,
                              const float* __restrict__ w011, const float* __restrict__ w101,
                              const float* __restrict__ lp0, const float* __restrict__ lp1,
                              float* __restrict__ tmp1) {
    int gid = blockIdx.x * 256 + threadIdx.x;
    int tslot = gid >> 15;
    int e = gid & 32767;
    int z = e & 31;
    int uv = e >> 5;
    int b = tslot >> 2, path = tslot & 3;
    const float* W = (path == 0 ? w000 : path == 1 ? w110 : path == 2 ? w011 : w101) + b * 32768;
    const float* L = ((path == 0 || path == 1) ? lp0 : lp1) + b * 1024;
    float scale = (path == 1) ? (1.0f / (8192.0f * 1.7320508075688772f)) : (1.0f / 8192.0f);
    const float* wr = W + uv * 32;
    float acc = 0.0f;
    for (int w = 0; w < 32; ++w) acc += wr[w] * L[w * 32 + z];
    tmp1[gid] = acc * scale;
}

__global__ void stageB_kernel(const float* __restrict__ ul0, const float* __restrict__ ul1,
                              const float* __restrict__ tmp1, float* __restrict__ tmp2) {
    int gid = blockIdx.x * 256 + threadIdx.x;
    int tslot = gid >> 15;
    int e = gid & 32767;
    int z = e & 31;
    int bb = (e >> 5) & 31;
    int u = e >> 10;
    int b = tslot >> 2, path = tslot & 3;
    const float* U = ((path == 0 || path == 3) ? ul0 : ul1) + b * 1024;
    const float* in = tmp1 + (size_t)tslot * 32768 + u * 1024 + z;
    float acc = 0.0f;
    for (int v = 0; v < 32; ++v) acc += U[bb * 32 + v] * in[v * 32];
    tmp2[gid] = acc;
}

__global__ void stageC_kernel(const float* __restrict__ hl0, const float* __restrict__ hl1,
                              const float* __restrict__ tmp2, float* __restrict__ Weff) {
    int gid = blockIdx.x * 256 + threadIdx.x;
    int tslot = gid >> 15;
    int e = gid & 32767;
    int z = e & 31;
    int bb = (e >> 5) & 31;
    int a = e >> 10;
    int b = tslot >> 2, path = tslot & 3;
    const float* H = ((path == 0 || path == 2) ? hl0 : hl1) + b * 1024;
    const float* in = tmp2 + (size_t)tslot * 32768 + bb * 32 + z;
    float acc = 0.0f;
    for (int u = 0; u < 32; ++u) acc += H[a * 32 + u] * in[u * 1024];
    Weff[gid] = acc;
}

// ---------------------------------------------------------------------------
// pack kernel: fp32 Weff / sc weights -> bf16, B-frag layouts (linear = col*32+k)
// per-b flat layout (151552 u16):
//  [0,32768):        W000T col=bb*32+z, k=a
//  [32768,65536):    W011T col=bb*32+z, k=a
//  [65536,98304):    W101T col=a*32+z,  k=bb
//  [98304,131072):   W110X col=a*32+z,  k=bb
//  [131072,141312):  WSC0P [s][col=z][k=a]  (x INV_SC)
//  [141312,151552):  WSC1P [s][col=z][k=a]  (x INV_SC)
// ---------------------------------------------------------------------------
__global__ void pack_kernel(const float* __restrict__ Weff,
                            const float* __restrict__ sc_w0, const float* __restrict__ sc_w1,
                            u16* __restrict__ packs, int total) {
    int gid = blockIdx.x * 256 + threadIdx.x;
    if (gid >= total) return;
    int b = gid / 151552;
    int e = gid - b * 151552;
    float v;
    if (e < 131072) {
        int which = e >> 15;          // 0:000 1:011 2:101 3:110
        int e2 = e & 32767;
        int k = e2 & 31;
        int z = (e2 >> 5) & 31;
        int hi = e2 >> 10;
        int path = (which == 0) ? 0 : (which == 1) ? 2 : (which == 2) ? 3 : 1;
        int a  = (which < 2) ? k  : hi;
        int bb = (which < 2) ? hi : k;
        v = Weff[(size_t)((b * 4 + path) * 32 + a) * 1024 + bb * 32 + z];
    } else {
        int e2 = e - 131072;
        int which = e2 / 10240;
        int e3 = e2 - which * 10240;
        int s = e3 >> 10, z = (e3 >> 5) & 31, a = e3 & 31;
        const float* S = which ? sc_w1 : sc_w0;
        v = S[(size_t)b * 10240 + a * 320 + s * 32 + z] * INV_SC;
    }
    packs[gid] = f2bf(v);
}

// ---------------------------------------------------------------------------
// MFMA TP + self-connection + stats kernel.  One WG (4 waves) per 16 nodes.
// EXACT R2 inner-loop structure (proven spill-free at VGPR=52), with:
//  * LDS shrunk 33792 -> 24576 B (epilogue red now 2 tiles + two-phase
//    cross-wave reduce) => 6 WGs/CU instead of 3 => 2x waves for latency
//    hiding (depth-1 L2 loads are TLP-hidden only).
//  * path-110 weight loads hoisted out of the c-loop (th-outer): -32
//    L2 loads per wave, same math.
//  * waves_per_eu(4) min-only: 128-reg allocator budget, no occupancy cap.
// ---------------------------------------------------------------------------
__attribute__((amdgpu_waves_per_eu(4)))
__global__ __launch_bounds__(256)
void tp_kernel(const float* __restrict__ hidden_b, const float* __restrict__ up,
               const u16* __restrict__ pk,
               const float* __restrict__ lp_b0,
               const int* __restrict__ species, const int* __restrict__ batch,
               float* __restrict__ S1b, float* __restrict__ S2b, float* __restrict__ V2b,
               float* __restrict__ zout, int N) {
    constexpr int OFF_000 = 0, OFF_011 = 32768, OFF_101 = 65536, OFF_110 = 98304;
    constexpr int OFF_SC0 = 131072, OFF_SC1 = 141312;

    __shared__ __align__(16) char smem[24576];
    __shared__ int spec_l[16];
    __shared__ int bat_l[16];
    __shared__ float gs1[NGRAPH], gs2[NGRAPH], gv2[NGRAPH];

    u16* sh_bf = (u16*)smem;                 // [16][40] bf16, A-layout
    u16* su_bf = (u16*)(smem + 1280);        // [16][40]
    u16* vu_bf = (u16*)(smem + 2560);        // [3][16][40]
    u16* vh_bf = (u16*)(smem + 6400);        // [3][16][40]
    float* suT = (float*)(smem + 10240);     // [32 bb][16 n] fp32 (Y)
    float* vuT = (float*)(smem + 12288);     // [3][32][16]
    float* vhT = (float*)(smem + 18432);     // [3][32][16]
    float* red = (float*)smem;               // [2][16][132] fp32 epilogue overlay (16896 B)

    const int t = threadIdx.x;
    const int w = t >> 6, lane = t & 63, quad = lane >> 4, c16 = lane & 15;
    const int n0 = blockIdx.x * 16;
    const int nvalid = min(16, N - n0);

    if (t < NGRAPH) { gs1[t] = 0.f; gs2[t] = 0.f; gv2[t] = 0.f; }
    if (t < 16) {
        spec_l[t] = (t < nvalid) ? species[n0 + t] : -1;
        bat_l[t]  = (t < nvalid) ? batch[n0 + t] : 0;
    }
    for (int i = t; i < 2048; i += 256) {
        int n = i >> 7, col = i & 127;
        float hv = 0.f, uv = 0.f;
        if (n < nvalid) {
            hv = hidden_b[(size_t)(n0 + n) * 128 + col];
            uv = up[(size_t)(n0 + n) * 128 + col];
        }
        if (col < 32) {
            sh_bf[n * 40 + col] = f2bf(hv); su_bf[n * 40 + col] = f2bf(uv);
            suT[col * 16 + n] = uv;
        } else {
            int idx = col - 32, c = idx % 3, a = idx / 3;
            vh_bf[(c * 16 + n) * 40 + a] = f2bf(hv);
            vu_bf[(c * 16 + n) * 40 + a] = f2bf(uv);
            vhT[(c * 32 + a) * 16 + n] = hv;
            vuT[(c * 32 + a) * 16 + n] = uv;
        }
    }
    __syncthreads();

    const v4f z4 = {0.f, 0.f, 0.f, 0.f};
    v4f o0[2];                    // [zh] -> out0[node=quad*4+r][z=zh*16+c16]
    v4f o1[3][2];                 // [c][zh]
    o0[0] = z4; o0[1] = z4;
#pragma unroll
    for (int c = 0; c < 3; ++c) { o1[c][0] = z4; o1[c][1] = z4; }

    v8bf a_sh = frag16(sh_bf + c16 * 40 + quad * 8);

    // ---- path 000: T=sh@W000 (col=bb*32+z), stage2 y=su ----
    {
        const u16* Wb = pk + OFF_000 + (w * 16 * 16 + c16) * 32 + quad * 8;
#pragma unroll 4
        for (int th = 0; th < 8; ++th) {
            int bb = w * 8 + th;
            v4f y = *(const v4f*)(suT + bb * 16 + quad * 4);
            v8bf bf0 = frag16(Wb + (th * 2) * 512);
            v8bf bf1 = frag16(Wb + (th * 2 + 1) * 512);
            v4f C0 = MFMA(a_sh, bf0, z4);
            v4f C1 = MFMA(a_sh, bf1, z4);
#pragma unroll
            for (int r = 0; r < 4; ++r) {
                o0[0][r] += C0[r] * y[r];
                o0[1][r] += C1[r] * y[r];
            }
        }
    }
    // ---- path 011: T=sh@W011 (col=bb*32+z), stage2 y=vu[c] x3 ----
    {
        const u16* Wb = pk + OFF_011 + (w * 16 * 16 + c16) * 32 + quad * 8;
#pragma unroll 2
        for (int th = 0; th < 8; ++th) {
            int bb = w * 8 + th;
            v8bf bf0 = frag16(Wb + (th * 2) * 512);
            v8bf bf1 = frag16(Wb + (th * 2 + 1) * 512);
            v4f C0 = MFMA(a_sh, bf0, z4);
            v4f C1 = MFMA(a_sh, bf1, z4);
#pragma unroll
            for (int c = 0; c < 3; ++c) {
                v4f y = *(const v4f*)(vuT + (c * 32 + bb) * 16 + quad * 4);
#pragma unroll
                for (int r = 0; r < 4; ++r) {
                    o1[c][0][r] += C0[r] * y[r];
                    o1[c][1][r] += C1[r] * y[r];
                }
            }
        }
    }
    // ---- path 101: T=su@W101 (col=a*32+z, k=bb), stage2 y=vh[c] x3 ----
    {
        v8bf a_su = frag16(su_bf + c16 * 40 + quad * 8);
        const u16* Wb = pk + OFF_101 + (w * 16 * 16 + c16) * 32 + quad * 8;
#pragma unroll 2
        for (int th = 0; th < 8; ++th) {
            int aa = w * 8 + th;
            v8bf bf0 = frag16(Wb + (th * 2) * 512);
            v8bf bf1 = frag16(Wb + (th * 2 + 1) * 512);
            v4f C0 = MFMA(a_su, bf0, z4);
            v4f C1 = MFMA(a_su, bf1, z4);
#pragma unroll
            for (int c = 0; c < 3; ++c) {
                v4f y = *(const v4f*)(vhT + (c * 32 + aa) * 16 + quad * 4);
#pragma unroll
                for (int r = 0; r < 4; ++r) {
                    o1[c][0][r] += C0[r] * y[r];
                    o1[c][1][r] += C1[r] * y[r];
                }
            }
        }
    }
    // ---- path 110 (T-form): th-outer, weights loaded ONCE, c inner ----
    {
        v8bf av0 = frag16(vu_bf + (0 * 16 + c16) * 40 + quad * 8);
        v8bf av1 = frag16(vu_bf + (1 * 16 + c16) * 40 + quad * 8);
        v8bf av2 = frag16(vu_bf + (2 * 16 + c16) * 40 + quad * 8);
        const u16* Wb = pk + OFF_110 + (w * 16 * 16 + c16) * 32 + quad * 8;
#pragma unroll 2
        for (int th = 0; th < 8; ++th) {
            int aa = w * 8 + th;
            v8bf bf0 = frag16(Wb + (th * 2) * 512);
            v8bf bf1 = frag16(Wb + (th * 2 + 1) * 512);
            v4f y0 = *(const v4f*)(vhT + (0 * 32 + aa) * 16 + quad * 4);
            v4f y1 = *(const v4f*)(vhT + (1 * 32 + aa) * 16 + quad * 4);
            v4f y2 = *(const v4f*)(vhT + (2 * 32 + aa) * 16 + quad * 4);
            v4f C00 = MFMA(av0, bf0, z4), C01 = MFMA(av0, bf1, z4);
            v4f C10 = MFMA(av1, bf0, z4), C11 = MFMA(av1, bf1, z4);
            v4f C20 = MFMA(av2, bf0, z4), C21 = MFMA(av2, bf1, z4);
#pragma unroll
            for (int r = 0; r < 4; ++r) {
                o0[0][r] += C00[r] * y0[r] + C10[r] * y1[r] + C20[r] * y2[r];
                o0[1][r] += C01[r] * y0[r] + C11[r] * y1[r] + C21[r] * y2[r];
            }
        }
    }
    // ---- self connection: species-masked A-frags, species split over waves ----
    {
        const int s0 = (w < 2) ? w * 3 : 6 + (w - 2) * 2;
        const int ns = (w < 2) ? 3 : 2;
        v8bf zf = __builtin_bit_cast(v8bf, (v4u_t){0u, 0u, 0u, 0u});
        int sp = spec_l[c16];
        v8bf a_vh0 = frag16(vh_bf + (0 * 16 + c16) * 40 + quad * 8);
        v8bf a_vh1 = frag16(vh_bf + (1 * 16 + c16) * 40 + quad * 8);
        v8bf a_vh2 = frag16(vh_bf + (2 * 16 + c16) * 40 + quad * 8);
        for (int si = s0; si < s0 + ns; ++si) {
            bool m = (sp == si);
            v8bf ash_m = m ? a_sh : zf;
            v8bf am0 = m ? a_vh0 : zf;
            v8bf am1 = m ? a_vh1 : zf;
            v8bf am2 = m ? a_vh2 : zf;
#pragma unroll
            for (int zh = 0; zh < 2; ++zh) {
                int boff = (si * 32 + zh * 16 + c16) * 32 + quad * 8;
                v8bf bf0 = frag16(pk + OFF_SC0 + boff);
                v8bf bf1 = frag16(pk + OFF_SC1 + boff);
                o0[zh] = MFMA(ash_m, bf0, o0[zh]);
                o1[0][zh] = MFMA(am0, bf1, o1[0][zh]);
                o1[1][zh] = MFMA(am1, bf1, o1[1][zh]);
                o1[2][zh] = MFMA(am2, bf1, o1[2][zh]);
            }
        }
    }

    // ---- epilogue: two-phase cross-wave reduce through 2-tile red ----
    __syncthreads();
    if (w < 2) {
#pragma unroll
        for (int r = 0; r < 4; ++r) {
            int n = quad * 4 + r;
            float* row = red + (w * 16 + n) * 132;
            row[c16]      = o0[0][r];
            row[16 + c16] = o0[1][r];
#pragma unroll
            for (int c = 0; c < 3; ++c) {
                row[32 + c16 * 3 + c]        = o1[c][0][r];
                row[32 + (16 + c16) * 3 + c] = o1[c][1][r];
            }
        }
    }
    __syncthreads();
    if (w >= 2) {
#pragma unroll
        for (int r = 0; r < 4; ++r) {
            int n = quad * 4 + r;
            float* row = red + ((w - 2) * 16 + n) * 132;
            row[c16]      += o0[0][r];
            row[16 + c16] += o0[1][r];
#pragma unroll
            for (int c = 0; c < 3; ++c) {
                row[32 + c16 * 3 + c]        += o1[c][0][r];
                row[32 + (16 + c16) * 3 + c] += o1[c][1][r];
            }
        }
    }
    __syncthreads();
    {
        int n = t >> 4, seg = t & 15;
        v4f sa = z4, sb = z4;
#pragma unroll
        for (int ww = 0; ww < 2; ++ww) {
            const float* rp = red + (ww * 16 + n) * 132 + seg * 8;
            sa += *(const v4f*)rp;
            sb += *(const v4f*)(rp + 4);
        }
        float s1p = 0.f, s2p = 0.f, v2p = 0.f;
        if (seg < 4) {
            sa += *(const v4f*)(lp_b0 + seg * 8);
            sb += *(const v4f*)(lp_b0 + seg * 8 + 4);
            s1p = sa[0] + sa[1] + sa[2] + sa[3] + sb[0] + sb[1] + sb[2] + sb[3];
            s2p = sa[0]*sa[0] + sa[1]*sa[1] + sa[2]*sa[2] + sa[3]*sa[3]
                + sb[0]*sb[0] + sb[1]*sb[1] + sb[2]*sb[2] + sb[3]*sb[3];
        } else {
            v2p = sa[0]*sa[0] + sa[1]*sa[1] + sa[2]*sa[2] + sa[3]*sa[3]
                + sb[0]*sb[0] + sb[1]*sb[1] + sb[2]*sb[2] + sb[3]*sb[3];
        }
        if (n < nvalid) {
            float* op = zout + (size_t)(n0 + n) * 128 + seg * 8;
            *(v4f*)op = sa;
            *(v4f*)(op + 4) = sb;
        }
#pragma unroll
        for (int off = 8; off >= 1; off >>= 1) {
            s1p += __shfl_xor(s1p, off, 16);
            s2p += __shfl_xor(s2p, off, 16);
            v2p += __shfl_xor(v2p, off, 16);
        }
        if (seg == 0 && n < nvalid) {
            int g = bat_l[n];
            atomicAdd(&gs1[g], s1p);
            atomicAdd(&gs2[g], s2p);
            atomicAdd(&gv2[g], v2p);
        }
    }
    __syncthreads();
    {
        const int bank = blockIdx.x & (NBANK - 1);
        if (t < NGRAPH) {
            if (gs1[t] != 0.f) atomicAdd(&S1b[bank * NGRAPH + t], gs1[t]);
            if (gs2[t] != 0.f) atomicAdd(&S2b[bank * NGRAPH + t], gs2[t]);
            if (gv2[t] != 0.f) atomicAdd(&V2b[bank * NGRAPH + t], gv2[t]);
        }
    }
}

// ---------------------------------------------------------------------------
// LayerNorm + skip kernel (in-place on z written by tp_kernel).
// Prologue reduces the replicated stat banks in-WG (L2-resident reads).
// ---------------------------------------------------------------------------
__global__ __launch_bounds__(256)
void norm_kernel(const float* __restrict__ hidden_b, float* __restrict__ out_b,
                 const float* __restrict__ skw0, const float* __restrict__ skb0,
                 const float* __restrict__ skw1,
                 const float* __restrict__ lnw0, const float* __restrict__ lnb0,
                 const float* __restrict__ lnw1,
                 const int* __restrict__ batch,
                 const float* __restrict__ S1b, const float* __restrict__ S2b,
                 const float* __restrict__ V2b, const float* __restrict__ cntb, int N) {
    __shared__ __align__(16) float sh_l[8][32];
    __shared__ __align__(16) float vh_l[8][96];
    __shared__ float stat_s[3][NGRAPH];
    __shared__ float cnt_s[NGRAPH];
    const int t = threadIdx.x, z = t & 31, nl = t >> 5;
    const int n0 = blockIdx.x * 8;
    for (int i = t; i < 8 * 128; i += 256) {
        int n = i >> 7, col = i & 127;
        float v = (n0 + n < N) ? hidden_b[(size_t)(n0 + n) * 128 + col] : 0.f;
        if (col < 32) sh_l[n][col] = v; else vh_l[n][col - 32] = v;
    }
    if (t < 48) {
        int arr = t >> 4, g = t & 15;
        const float* base = (arr == 0) ? S1b : (arr == 1) ? S2b : V2b;
        float s = 0.f;
        for (int k = 0; k < NBANK; ++k) s += base[k * NGRAPH + g];
        stat_s[arr][g] = s;
    } else if (t < 64) {
        int g = t - 48;
        float c = 0.f;
        for (int k = 0; k < NCBANK; ++k) c += cntb[k * NGRAPH + g];
        cnt_s[g] = c;
    }
    __syncthreads();
    const int n = n0 + nl;
    if (n >= N) return;

    float sk0 = 0.f, s1 = 0.f, s2 = 0.f, s3 = 0.f;
    for (int a = 0; a < 32; ++a) {
        float w0 = skw0[a * 32 + z];
        float w1 = skw1[a * 32 + z];
        sk0 += sh_l[nl][a] * w0;
        s1 += vh_l[nl][a * 3 + 0] * w1;
        s2 += vh_l[nl][a * 3 + 1] * w1;
        s3 += vh_l[nl][a * 3 + 2] * w1;
    }
    int g = batch[n];
    float cM = fmaxf(cnt_s[g], 1.0f) * 32.0f;
    float mean = stat_s[0][g] / cM;
    float var = fmaxf(stat_s[1][g] / cM - mean * mean, 0.0f);
    float rs = rsqrtf(var + 1e-5f);
    float rv = rsqrtf(fmaxf(stat_s[2][g] / cM, 0.0f) + 1e-5f);

    size_t base = (size_t)n * 128;
    float z0 = out_b[base + z];
    out_b[base + z] = (z0 - mean) * rs * lnw0[z] + lnb0[z] + sk0 * INV32S + skb0[z];
    float lw = lnw1[z] * rv;
    float x0 = out_b[base + 32 + z * 3 + 0];
    float x1 = out_b[base + 32 + z * 3 + 1];
    float x2 = out_b[base + 32 + z * 3 + 2];
    out_b[base + 32 + z * 3 + 0] = x0 * lw + s1 * INV32S;
    out_b[base + 32 + z * 3 + 1] = x1 * lw + s2 * INV32S;
    out_b[base + 32 + z * 3 + 2] = x2 * lw + s3 * INV32S;
}

// ---------------------------------------------------------------------------
// Workspace layout (total = 2 MiB + 25.6 KiB for B=2):
//   tmp1  [0,       1 MiB)  : stageA out; REUSED as Weff (stageC out)
//   tmp2  [1 MiB,   2 MiB)  : stageB out; REUSED as bf16 packs (pack out)
//   cntb  [2 MiB, +1 KiB)   : cnt banks [NCBANK][16]
//   S1b/S2b/V2b             : stat banks [B][NBANK][16] each
// ---------------------------------------------------------------------------
extern "C" void kernel_launch(void* const* d_in, const int* in_sizes, int n_in,
                              void* d_out, int out_size, void* d_ws, size_t ws_size,
                              hipStream_t stream) {
    const float* hidden = (const float*)d_in[0];
    const float* up0    = (const float*)d_in[1];
    const float* hl_w0  = (const float*)d_in[2];
    const float* hl_w1  = (const float*)d_in[3];
    const float* ul_w0  = (const float*)d_in[4];
    const float* ul_w1  = (const float*)d_in[5];
    const float* w000   = (const float*)d_in[6];
    const float* w110   = (const float*)d_in[7];
    const float* w011   = (const float*)d_in[8];
    const float* w101   = (const float*)d_in[9];
    const float* lp_w0  = (const float*)d_in[10];
    const float* lp_b0  = (const float*)d_in[11];
    const float* lp_w1  = (const float*)d_in[12];
    const float* sc_w0  = (const float*)d_in[13];
    const float* sc_w1  = (const float*)d_in[14];
    const float* ln_w0  = (const float*)d_in[15];
    const float* ln_b0  = (const float*)d_in[16];
    const float* ln_w1  = (const float*)d_in[17];
    const float* sk_w0  = (const float*)d_in[18];
    const float* sk_b0  = (const float*)d_in[19];
    const float* sk_w1  = (const float*)d_in[20];
    const int* species  = (const int*)d_in[21];
    const int* batch    = (const int*)d_in[22];
    float* out = (float*)d_out;

    const int N = in_sizes[21];
    const int B = in_sizes[0] / (N * 128);

    float* ws = (float*)d_ws;
    float* tmp1 = ws;                                  // stageA out -> Weff
    float* tmp2 = tmp1 + (size_t)B * 4 * 32768;        // stageB out -> packs
    float* cntb = tmp2 + (size_t)B * 4 * 32768;        // [NCBANK][16]
    float* S1b = cntb + NCBANK * NGRAPH;               // [B][NBANK][16]
    float* S2b = S1b + (size_t)B * NBANK * NGRAPH;
    float* V2b = S2b + (size_t)B * NBANK * NGRAPH;
    int statn = NCBANK * NGRAPH + 3 * B * NBANK * NGRAPH;

    zero_kernel<<<(statn + 255) / 256, 256, 0, stream>>>(cntb, statn);
    count_kernel<<<(N + 255) / 256, 256, 0, stream>>>(batch, cntb, N);

    int nb = B * 4 * 32768 / 256;
    stageA_kernel<<<nb, 256, 0, stream>>>(w000, w110, w011, w101, lp_w0, lp_w1, tmp1);
    stageB_kernel<<<nb, 256, 0, stream>>>(ul_w0, ul_w1, tmp1, tmp2);
    stageC_kernel<<<nb, 256, 0, stream>>>(hl_w0, hl_w1, tmp2, tmp1);   // Weff -> tmp1

    u16* packs = (u16*)tmp2;                           // tmp2 dead after stageC
    int ptotal = B * 151552;
    pack_kernel<<<(ptotal + 255) / 256, 256, 0, stream>>>(tmp1, sc_w0, sc_w1, packs, ptotal);

    for (int b = 0; b < B; ++b) {
        const float* up = (b == 0) ? up0 : out + (size_t)(b - 1) * N * 128;
        const u16* pb = packs + (size_t)b * 151552;
        tp_kernel<<<(N + 15) / 16, 256, 0, stream>>>(
            hidden + (size_t)b * N * 128, up, pb,
            lp_b0 + b * MULT, species, batch,
            S1b + (size_t)b * NBANK * NGRAPH, S2b + (size_t)b * NBANK * NGRAPH,
            V2b + (size_t)b * NBANK * NGRAPH,
            out + (size_t)b * N * 128, N);
        norm_kernel<<<(N + 7) / 8, 256, 0, stream>>>(
            hidden + (size_t)b * N * 128, out + (size_t)b * N * 128,
            sk_w0 + b * 1024, sk_b0 + b * MULT, sk_w1 + b * 1024,
            ln_w0 + b * MULT, ln_b0 + b * MULT, ln_w1 + b * MULT,
            batch, S1b + (size_t)b * NBANK * NGRAPH, S2b + (size_t)b * NBANK * NGRAPH,
            V2b + (size_t)b * NBANK * NGRAPH, cntb, N);
    }
}

// Round 8
// 381.385 us; speedup vs baseline: 4.6269x; 1.0100x over previous
//
#include <hip/hip_runtime.h>
#include <math.h>

#define MULT 32
#define NSPEC 10
#define NGRAPH 16
#define NBANK 64          /* stat replication banks (tp_kernel) */
#define NCBANK 16         /* cnt replication banks (count_kernel) */
#define INV_SC 0.05590169943749474f   /* 1/sqrt(32*10) */
#define INV32S 0.17677669529663687f   /* 1/sqrt(32) */

typedef unsigned short u16;
typedef __bf16 v8bf __attribute__((ext_vector_type(8)));
typedef float v4f __attribute__((ext_vector_type(4)));
typedef unsigned int v4u_t __attribute__((ext_vector_type(4)));

__device__ __forceinline__ u16 f2bf(float f) {
    unsigned int u = __builtin_bit_cast(unsigned int, f);
    unsigned int r = u + 0x7fffu + ((u >> 16) & 1u);
    return (u16)(r >> 16);
}

__device__ __forceinline__ v8bf frag16(const u16* p) {
    return __builtin_bit_cast(v8bf, *(const v4u_t*)p);
}

#define MFMA(a, b, c) __builtin_amdgcn_mfma_f32_16x16x32_bf16(a, b, c, 0, 0, 0)

// ---------------------------------------------------------------------------
// small utility kernels
// ---------------------------------------------------------------------------
__global__ void zero_kernel(float* __restrict__ p, int n) {
    int i = blockIdx.x * 256 + threadIdx.x;
    if (i < n) p[i] = 0.0f;
}

__global__ void count_kernel(const int* __restrict__ batch, float* __restrict__ cntb, int N) {
    __shared__ int bins[NGRAPH];
    int t = threadIdx.x;
    if (t < NGRAPH) bins[t] = 0;
    __syncthreads();
    int i = blockIdx.x * 256 + t;
    if (i < N) atomicAdd(&bins[batch[i]], 1);
    __syncthreads();
    int bank = blockIdx.x & (NCBANK - 1);
    if (t < NGRAPH && bins[t] > 0) atomicAdd(&cntb[bank * NGRAPH + t], (float)bins[t]);
}

// ---------------------------------------------------------------------------
// effective-weight precompute (fp32):
//  Weff[path,b][a,bb,z], path: 0=000, 1=110, 2=011, 3=101
// ---------------------------------------------------------------------------
__global__ void stageA_kernel(const float* __restrict__ w000, const float* __restrict__ w110,
                              const float* __restrict__ w011, const float* __restrict__ w101,
                              const float* __restrict__ lp0, const float* __restrict__ lp1,
                              float* __restrict__ tmp1) {
    int gid = blockIdx.x * 256 + threadIdx.x;
    int tslot = gid >> 15;
    int e = gid & 32767;
    int z = e & 31;
    int uv = e >> 5;
    int b = tslot >> 2, path = tslot & 3;
    const float* W = (path == 0 ? w000 : path == 1 ? w110 : path == 2 ? w011 : w101) + b * 32768;
    const float* L = ((path == 0 || path == 1) ? lp0 : lp1) + b * 1024;
    float scale = (path == 1) ? (1.0f / (8192.0f * 1.7320508075688772f)) : (1.0f / 8192.0f);
    const float* wr = W + uv * 32;
    float acc = 0.0f;
    for (int w = 0; w < 32; ++w) acc += wr[w] * L[w * 32 + z];
    tmp1[gid] = acc * scale;
}

__global__ void stageB_kernel(const float* __restrict__ ul0, const float* __restrict__ ul1,
                              const float* __restrict__ tmp1, float* __restrict__ tmp2) {
    int gid = blockIdx.x * 256 + threadIdx.x;
    int tslot = gid >> 15;
    int e = gid & 32767;
    int z = e & 31;
    int bb = (e >> 5) & 31;
    int u = e >> 10;
    int b = tslot >> 2, path = tslot & 3;
    const float* U = ((path == 0 || path == 3) ? ul0 : ul1) + b * 1024;
    const float* in = tmp1 + (size_t)tslot * 32768 + u * 1024 + z;
    float acc = 0.0f;
    for (int v = 0; v < 32; ++v) acc += U[bb * 32 + v] * in[v * 32];
    tmp2[gid] = acc;
}

__global__ void stageC_kernel(const float* __restrict__ hl0, const float* __restrict__ hl1,
                              const float* __restrict__ tmp2, float* __restrict__ Weff) {
    int gid = blockIdx.x * 256 + threadIdx.x;
    int tslot = gid >> 15;
    int e = gid & 32767;
    int z = e & 31;
    int bb = (e >> 5) & 31;
    int a = e >> 10;
    int b = tslot >> 2, path = tslot & 3;
    const float* H = ((path == 0 || path == 2) ? hl0 : hl1) + b * 1024;
    const float* in = tmp2 + (size_t)tslot * 32768 + bb * 32 + z;
    float acc = 0.0f;
    for (int u = 0; u < 32; ++u) acc += H[a * 32 + u] * in[u * 1024];
    Weff[gid] = acc;
}

// ---------------------------------------------------------------------------
// pack kernel: fp32 Weff / sc weights -> bf16, B-frag layouts (linear = col*32+k)
// per-b flat layout (151552 u16):
//  [0,32768):        W000T col=bb*32+z, k=a
//  [32768,65536):    W011T col=bb*32+z, k=a
//  [65536,98304):    W101T col=a*32+z,  k=bb
//  [98304,131072):   W110X col=a*32+z,  k=bb
//  [131072,141312):  WSC0P [s][col=z][k=a]  (x INV_SC)
//  [141312,151552):  WSC1P [s][col=z][k=a]  (x INV_SC)
// ---------------------------------------------------------------------------
__global__ void pack_kernel(const float* __restrict__ Weff,
                            const float* __restrict__ sc_w0, const float* __restrict__ sc_w1,
                            u16* __restrict__ packs, int total) {
    int gid = blockIdx.x * 256 + threadIdx.x;
    if (gid >= total) return;
    int b = gid / 151552;
    int e = gid - b * 151552;
    float v;
    if (e < 131072) {
        int which = e >> 15;          // 0:000 1:011 2:101 3:110
        int e2 = e & 32767;
        int k = e2 & 31;
        int z = (e2 >> 5) & 31;
        int hi = e2 >> 10;
        int path = (which == 0) ? 0 : (which == 1) ? 2 : (which == 2) ? 3 : 1;
        int a  = (which < 2) ? k  : hi;
        int bb = (which < 2) ? hi : k;
        v = Weff[(size_t)((b * 4 + path) * 32 + a) * 1024 + bb * 32 + z];
    } else {
        int e2 = e - 131072;
        int which = e2 / 10240;
        int e3 = e2 - which * 10240;
        int s = e3 >> 10, z = (e3 >> 5) & 31, a = e3 & 31;
        const float* S = which ? sc_w1 : sc_w0;
        v = S[(size_t)b * 10240 + a * 320 + s * 32 + z] * INV_SC;
    }
    packs[gid] = f2bf(v);
}

// ---------------------------------------------------------------------------
// MFMA TP + self-connection + stats kernel.  One WG (4 waves) per 32 nodes
// (TWO 16-node tiles A/B).  R7's proven loop structure; each weight fragment
// load (the serialized-latency bottleneck: depth~1, ~650cy L2) now feeds
// MFMAs for BOTH tiles -> weight-load latency per node HALVES.  A-frags and
// accumulators duplicated with named A/B suffixes (no runtime-indexed arrays
// -> nothing to demote to scratch).  waves_per_eu(3): ~168-reg budget.
// ---------------------------------------------------------------------------
__attribute__((amdgpu_waves_per_eu(3)))
__global__ __launch_bounds__(256)
void tp_kernel(const float* __restrict__ hidden_b, const float* __restrict__ up,
               const u16* __restrict__ pk,
               const float* __restrict__ lp_b0,
               const int* __restrict__ species, const int* __restrict__ batch,
               float* __restrict__ S1b, float* __restrict__ S2b, float* __restrict__ V2b,
               float* __restrict__ zout, int N) {
    constexpr int OFF_000 = 0, OFF_011 = 32768, OFF_101 = 65536, OFF_110 = 98304;
    constexpr int OFF_SC0 = 131072, OFF_SC1 = 141312;

    __shared__ __align__(16) char smem[49152];
    __shared__ int spec_l[32];
    __shared__ int bat_l[32];
    __shared__ float gs1[NGRAPH], gs2[NGRAPH], gv2[NGRAPH];

    u16* sh_bf = (u16*)smem;                 // [2][16][40] bf16 (tile stride 640)
    u16* su_bf = (u16*)(smem + 2560);        // [2][16][40]
    u16* vu_bf = (u16*)(smem + 5120);        // [2][3][16][40] (tile stride 1920)
    u16* vh_bf = (u16*)(smem + 12800);       // [2][3][16][40]
    float* suT = (float*)(smem + 20480);     // [2][32][16] fp32 (tile stride 512)
    float* vuT = (float*)(smem + 24576);     // [2][3][32][16] (tile stride 1536)
    float* vhT = (float*)(smem + 36864);     // [2][3][32][16]
    float* red = (float*)smem;               // [2][32][132] fp32 epilogue overlay (33792 B)

    const int t = threadIdx.x;
    const int w = t >> 6, lane = t & 63, quad = lane >> 4, c16 = lane & 15;
    const int n0 = blockIdx.x * 32;
    const int nvalid = min(32, N - n0);

    if (t < NGRAPH) { gs1[t] = 0.f; gs2[t] = 0.f; gv2[t] = 0.f; }
    if (t < 32) {
        spec_l[t] = (t < nvalid) ? species[n0 + t] : -1;
        bat_l[t]  = (t < nvalid) ? batch[n0 + t] : 0;
    }
    for (int i = t; i < 4096; i += 256) {
        int n = i >> 7, col = i & 127;
        int tile = n >> 4, nl = n & 15;
        float hv = 0.f, uv = 0.f;
        if (n < nvalid) {
            hv = hidden_b[(size_t)(n0 + n) * 128 + col];
            uv = up[(size_t)(n0 + n) * 128 + col];
        }
        if (col < 32) {
            sh_bf[tile * 640 + nl * 40 + col] = f2bf(hv);
            su_bf[tile * 640 + nl * 40 + col] = f2bf(uv);
            suT[tile * 512 + col * 16 + nl] = uv;
        } else {
            int idx = col - 32, c = idx % 3, a = idx / 3;
            vh_bf[tile * 1920 + (c * 16 + nl) * 40 + a] = f2bf(hv);
            vu_bf[tile * 1920 + (c * 16 + nl) * 40 + a] = f2bf(uv);
            vhT[tile * 1536 + (c * 32 + a) * 16 + nl] = hv;
            vuT[tile * 1536 + (c * 32 + a) * 16 + nl] = uv;
        }
    }
    __syncthreads();

    const v4f z4 = {0.f, 0.f, 0.f, 0.f};
    v4f o0A[2], o1A[3][2], o0B[2], o1B[3][2];
    o0A[0] = z4; o0A[1] = z4; o0B[0] = z4; o0B[1] = z4;
#pragma unroll
    for (int c = 0; c < 3; ++c) {
        o1A[c][0] = z4; o1A[c][1] = z4;
        o1B[c][0] = z4; o1B[c][1] = z4;
    }

    v8bf a_shA = frag16(sh_bf + c16 * 40 + quad * 8);
    v8bf a_shB = frag16(sh_bf + 640 + c16 * 40 + quad * 8);

    // ---- path 000: T=sh@W000 (col=bb*32+z), stage2 y=su ----
    {
        const u16* Wb = pk + OFF_000 + (w * 256 + c16) * 32 + quad * 8;
#pragma unroll 4
        for (int th = 0; th < 8; ++th) {
            int bb = w * 8 + th;
            v8bf bf0 = frag16(Wb + (th * 2) * 512);
            v8bf bf1 = frag16(Wb + (th * 2 + 1) * 512);
            v4f yA = *(const v4f*)(suT + bb * 16 + quad * 4);
            v4f yB = *(const v4f*)(suT + 512 + bb * 16 + quad * 4);
            v4f C0 = MFMA(a_shA, bf0, z4), C1 = MFMA(a_shA, bf1, z4);
            v4f D0 = MFMA(a_shB, bf0, z4), D1 = MFMA(a_shB, bf1, z4);
#pragma unroll
            for (int r = 0; r < 4; ++r) {
                o0A[0][r] += C0[r] * yA[r]; o0A[1][r] += C1[r] * yA[r];
                o0B[0][r] += D0[r] * yB[r]; o0B[1][r] += D1[r] * yB[r];
            }
        }
    }
    // ---- path 011: T=sh@W011 (col=bb*32+z), stage2 y=vu[c] x3 ----
    {
        const u16* Wb = pk + OFF_011 + (w * 256 + c16) * 32 + quad * 8;
#pragma unroll 2
        for (int th = 0; th < 8; ++th) {
            int bb = w * 8 + th;
            v8bf bf0 = frag16(Wb + (th * 2) * 512);
            v8bf bf1 = frag16(Wb + (th * 2 + 1) * 512);
            v4f C0 = MFMA(a_shA, bf0, z4), C1 = MFMA(a_shA, bf1, z4);
            v4f D0 = MFMA(a_shB, bf0, z4), D1 = MFMA(a_shB, bf1, z4);
#pragma unroll
            for (int c = 0; c < 3; ++c) {
                v4f yA = *(const v4f*)(vuT + (c * 32 + bb) * 16 + quad * 4);
                v4f yB = *(const v4f*)(vuT + 1536 + (c * 32 + bb) * 16 + quad * 4);
#pragma unroll
                for (int r = 0; r < 4; ++r) {
                    o1A[c][0][r] += C0[r] * yA[r]; o1A[c][1][r] += C1[r] * yA[r];
                    o1B[c][0][r] += D0[r] * yB[r]; o1B[c][1][r] += D1[r] * yB[r];
                }
            }
        }
    }
    // ---- path 101: T=su@W101 (col=a*32+z, k=bb), stage2 y=vh[c] x3 ----
    {
        v8bf a_suA = frag16(su_bf + c16 * 40 + quad * 8);
        v8bf a_suB = frag16(su_bf + 640 + c16 * 40 + quad * 8);
        const u16* Wb = pk + OFF_101 + (w * 256 + c16) * 32 + quad * 8;
#pragma unroll 2
        for (int th = 0; th < 8; ++th) {
            int aa = w * 8 + th;
            v8bf bf0 = frag16(Wb + (th * 2) * 512);
            v8bf bf1 = frag16(Wb + (th * 2 + 1) * 512);
            v4f C0 = MFMA(a_suA, bf0, z4), C1 = MFMA(a_suA, bf1, z4);
            v4f D0 = MFMA(a_suB, bf0, z4), D1 = MFMA(a_suB, bf1, z4);
#pragma unroll
            for (int c = 0; c < 3; ++c) {
                v4f yA = *(const v4f*)(vhT + (c * 32 + aa) * 16 + quad * 4);
                v4f yB = *(const v4f*)(vhT + 1536 + (c * 32 + aa) * 16 + quad * 4);
#pragma unroll
                for (int r = 0; r < 4; ++r) {
                    o1A[c][0][r] += C0[r] * yA[r]; o1A[c][1][r] += C1[r] * yA[r];
                    o1B[c][0][r] += D0[r] * yB[r]; o1B[c][1][r] += D1[r] * yB[r];
                }
            }
        }
    }
    // ---- path 110 (T-form): th-outer, weights loaded ONCE, both tiles ----
    {
        v8bf avA0 = frag16(vu_bf + (0 * 16 + c16) * 40 + quad * 8);
        v8bf avA1 = frag16(vu_bf + (1 * 16 + c16) * 40 + quad * 8);
        v8bf avA2 = frag16(vu_bf + (2 * 16 + c16) * 40 + quad * 8);
        v8bf avB0 = frag16(vu_bf + 1920 + (0 * 16 + c16) * 40 + quad * 8);
        v8bf avB1 = frag16(vu_bf + 1920 + (1 * 16 + c16) * 40 + quad * 8);
        v8bf avB2 = frag16(vu_bf + 1920 + (2 * 16 + c16) * 40 + quad * 8);
        const u16* Wb = pk + OFF_110 + (w * 256 + c16) * 32 + quad * 8;
#pragma unroll 2
        for (int th = 0; th < 8; ++th) {
            int aa = w * 8 + th;
            v8bf bf0 = frag16(Wb + (th * 2) * 512);
            v8bf bf1 = frag16(Wb + (th * 2 + 1) * 512);
            {
                v4f y0 = *(const v4f*)(vhT + (0 * 32 + aa) * 16 + quad * 4);
                v4f y1 = *(const v4f*)(vhT + (1 * 32 + aa) * 16 + quad * 4);
                v4f y2 = *(const v4f*)(vhT + (2 * 32 + aa) * 16 + quad * 4);
                v4f C00 = MFMA(avA0, bf0, z4), C01 = MFMA(avA0, bf1, z4);
                v4f C10 = MFMA(avA1, bf0, z4), C11 = MFMA(avA1, bf1, z4);
                v4f C20 = MFMA(avA2, bf0, z4), C21 = MFMA(avA2, bf1, z4);
#pragma unroll
                for (int r = 0; r < 4; ++r) {
                    o0A[0][r] += C00[r] * y0[r] + C10[r] * y1[r] + C20[r] * y2[r];
                    o0A[1][r] += C01[r] * y0[r] + C11[r] * y1[r] + C21[r] * y2[r];
                }
            }
            {
                v4f y0 = *(const v4f*)(vhT + 1536 + (0 * 32 + aa) * 16 + quad * 4);
                v4f y1 = *(const v4f*)(vhT + 1536 + (1 * 32 + aa) * 16 + quad * 4);
                v4f y2 = *(const v4f*)(vhT + 1536 + (2 * 32 + aa) * 16 + quad * 4);
                v4f C00 = MFMA(avB0, bf0, z4), C01 = MFMA(avB0, bf1, z4);
                v4f C10 = MFMA(avB1, bf0, z4), C11 = MFMA(avB1, bf1, z4);
                v4f C20 = MFMA(avB2, bf0, z4), C21 = MFMA(avB2, bf1, z4);
#pragma unroll
                for (int r = 0; r < 4; ++r) {
                    o0B[0][r] += C00[r] * y0[r] + C10[r] * y1[r] + C20[r] * y2[r];
                    o0B[1][r] += C01[r] * y0[r] + C11[r] * y1[r] + C21[r] * y2[r];
                }
            }
        }
    }
    // ---- self connection: species-masked A-frags, species split over waves ----
    {
        const int s0 = (w < 2) ? w * 3 : 6 + (w - 2) * 2;
        const int ns = (w < 2) ? 3 : 2;
        v8bf zf = __builtin_bit_cast(v8bf, (v4u_t){0u, 0u, 0u, 0u});
        int spA = spec_l[c16];
        int spB = spec_l[16 + c16];
        v8bf a_vhA0 = frag16(vh_bf + (0 * 16 + c16) * 40 + quad * 8);
        v8bf a_vhA1 = frag16(vh_bf + (1 * 16 + c16) * 40 + quad * 8);
        v8bf a_vhA2 = frag16(vh_bf + (2 * 16 + c16) * 40 + quad * 8);
        v8bf a_vhB0 = frag16(vh_bf + 1920 + (0 * 16 + c16) * 40 + quad * 8);
        v8bf a_vhB1 = frag16(vh_bf + 1920 + (1 * 16 + c16) * 40 + quad * 8);
        v8bf a_vhB2 = frag16(vh_bf + 1920 + (2 * 16 + c16) * 40 + quad * 8);
        for (int si = s0; si < s0 + ns; ++si) {
            bool mA = (spA == si), mB = (spB == si);
            v8bf ashA_m = mA ? a_shA : zf;
            v8bf amA0 = mA ? a_vhA0 : zf;
            v8bf amA1 = mA ? a_vhA1 : zf;
            v8bf amA2 = mA ? a_vhA2 : zf;
            v8bf ashB_m = mB ? a_shB : zf;
            v8bf amB0 = mB ? a_vhB0 : zf;
            v8bf amB1 = mB ? a_vhB1 : zf;
            v8bf amB2 = mB ? a_vhB2 : zf;
#pragma unroll
            for (int zh = 0; zh < 2; ++zh) {
                int boff = (si * 32 + zh * 16 + c16) * 32 + quad * 8;
                v8bf bf0 = frag16(pk + OFF_SC0 + boff);
                v8bf bf1 = frag16(pk + OFF_SC1 + boff);
                o0A[zh] = MFMA(ashA_m, bf0, o0A[zh]);
                o1A[0][zh] = MFMA(amA0, bf1, o1A[0][zh]);
                o1A[1][zh] = MFMA(amA1, bf1, o1A[1][zh]);
                o1A[2][zh] = MFMA(amA2, bf1, o1A[2][zh]);
                o0B[zh] = MFMA(ashB_m, bf0, o0B[zh]);
                o1B[0][zh] = MFMA(amB0, bf1, o1B[0][zh]);
                o1B[1][zh] = MFMA(amB1, bf1, o1B[1][zh]);
                o1B[2][zh] = MFMA(amB2, bf1, o1B[2][zh]);
            }
        }
    }

    // ---- epilogue: two-phase cross-wave reduce through [2][32][132] red ----
    __syncthreads();
    if (w < 2) {
#pragma unroll
        for (int r = 0; r < 4; ++r) {
            int n = quad * 4 + r;
            float* rowA = red + (w * 32 + n) * 132;
            float* rowB = red + (w * 32 + 16 + n) * 132;
            rowA[c16]      = o0A[0][r];
            rowA[16 + c16] = o0A[1][r];
            rowB[c16]      = o0B[0][r];
            rowB[16 + c16] = o0B[1][r];
#pragma unroll
            for (int c = 0; c < 3; ++c) {
                rowA[32 + c16 * 3 + c]        = o1A[c][0][r];
                rowA[32 + (16 + c16) * 3 + c] = o1A[c][1][r];
                rowB[32 + c16 * 3 + c]        = o1B[c][0][r];
                rowB[32 + (16 + c16) * 3 + c] = o1B[c][1][r];
            }
        }
    }
    __syncthreads();
    if (w >= 2) {
#pragma unroll
        for (int r = 0; r < 4; ++r) {
            int n = quad * 4 + r;
            float* rowA = red + ((w - 2) * 32 + n) * 132;
            float* rowB = red + ((w - 2) * 32 + 16 + n) * 132;
            rowA[c16]      += o0A[0][r];
            rowA[16 + c16] += o0A[1][r];
            rowB[c16]      += o0B[0][r];
            rowB[16 + c16] += o0B[1][r];
#pragma unroll
            for (int c = 0; c < 3; ++c) {
                rowA[32 + c16 * 3 + c]        += o1A[c][0][r];
                rowA[32 + (16 + c16) * 3 + c] += o1A[c][1][r];
                rowB[32 + c16 * 3 + c]        += o1B[c][0][r];
                rowB[32 + (16 + c16) * 3 + c] += o1B[c][1][r];
            }
        }
    }
    __syncthreads();
    {
        int nl = t >> 4, seg = t & 15;
#pragma unroll
        for (int tile = 0; tile < 2; ++tile) {
            int node = tile * 16 + nl;
            v4f sa = z4, sb = z4;
#pragma unroll
            for (int ww = 0; ww < 2; ++ww) {
                const float* rp = red + (ww * 32 + node) * 132 + seg * 8;
                sa += *(const v4f*)rp;
                sb += *(const v4f*)(rp + 4);
            }
            float s1p = 0.f, s2p = 0.f, v2p = 0.f;
            if (seg < 4) {
                sa += *(const v4f*)(lp_b0 + seg * 8);
                sb += *(const v4f*)(lp_b0 + seg * 8 + 4);
                s1p = sa[0] + sa[1] + sa[2] + sa[3] + sb[0] + sb[1] + sb[2] + sb[3];
                s2p = sa[0]*sa[0] + sa[1]*sa[1] + sa[2]*sa[2] + sa[3]*sa[3]
                    + sb[0]*sb[0] + sb[1]*sb[1] + sb[2]*sb[2] + sb[3]*sb[3];
            } else {
                v2p = sa[0]*sa[0] + sa[1]*sa[1] + sa[2]*sa[2] + sa[3]*sa[3]
                    + sb[0]*sb[0] + sb[1]*sb[1] + sb[2]*sb[2] + sb[3]*sb[3];
            }
            if (node < nvalid) {
                float* op = zout + (size_t)(n0 + node) * 128 + seg * 8;
                *(v4f*)op = sa;
                *(v4f*)(op + 4) = sb;
            }
#pragma unroll
            for (int off = 8; off >= 1; off >>= 1) {
                s1p += __shfl_xor(s1p, off, 16);
                s2p += __shfl_xor(s2p, off, 16);
                v2p += __shfl_xor(v2p, off, 16);
            }
            if (seg == 0 && node < nvalid) {
                int g = bat_l[node];
                atomicAdd(&gs1[g], s1p);
                atomicAdd(&gs2[g], s2p);
                atomicAdd(&gv2[g], v2p);
            }
        }
    }
    __syncthreads();
    {
        const int bank = blockIdx.x & (NBANK - 1);
        if (t < NGRAPH) {
            if (gs1[t] != 0.f) atomicAdd(&S1b[bank * NGRAPH + t], gs1[t]);
            if (gs2[t] != 0.f) atomicAdd(&S2b[bank * NGRAPH + t], gs2[t]);
            if (gv2[t] != 0.f) atomicAdd(&V2b[bank * NGRAPH + t], gv2[t]);
        }
    }
}

// ---------------------------------------------------------------------------
// LayerNorm + skip kernel (in-place on z written by tp_kernel).
// Prologue reduces the replicated stat banks in-WG (L2-resident reads).
// ---------------------------------------------------------------------------
__global__ __launch_bounds__(256)
void norm_kernel(const float* __restrict__ hidden_b, float* __restrict__ out_b,
                 const float* __restrict__ skw0, const float* __restrict__ skb0,
                 const float* __restrict__ skw1,
                 const float* __restrict__ lnw0, const float* __restrict__ lnb0,
                 const float* __restrict__ lnw1,
                 const int* __restrict__ batch,
                 const float* __restrict__ S1b, const float* __restrict__ S2b,
                 const float* __restrict__ V2b, const float* __restrict__ cntb, int N) {
    __shared__ __align__(16) float sh_l[8][32];
    __shared__ __align__(16) float vh_l[8][96];
    __shared__ float stat_s[3][NGRAPH];
    __shared__ float cnt_s[NGRAPH];
    const int t = threadIdx.x, z = t & 31, nl = t >> 5;
    const int n0 = blockIdx.x * 8;
    for (int i = t; i < 8 * 128; i += 256) {
        int n = i >> 7, col = i & 127;
        float v = (n0 + n < N) ? hidden_b[(size_t)(n0 + n) * 128 + col] : 0.f;
        if (col < 32) sh_l[n][col] = v; else vh_l[n][col - 32] = v;
    }
    if (t < 48) {
        int arr = t >> 4, g = t & 15;
        const float* base = (arr == 0) ? S1b : (arr == 1) ? S2b : V2b;
        float s = 0.f;
        for (int k = 0; k < NBANK; ++k) s += base[k * NGRAPH + g];
        stat_s[arr][g] = s;
    } else if (t < 64) {
        int g = t - 48;
        float c = 0.f;
        for (int k = 0; k < NCBANK; ++k) c += cntb[k * NGRAPH + g];
        cnt_s[g] = c;
    }
    __syncthreads();
    const int n = n0 + nl;
    if (n >= N) return;

    float sk0 = 0.f, s1 = 0.f, s2 = 0.f, s3 = 0.f;
    for (int a = 0; a < 32; ++a) {
        float w0 = skw0[a * 32 + z];
        float w1 = skw1[a * 32 + z];
        sk0 += sh_l[nl][a] * w0;
        s1 += vh_l[nl][a * 3 + 0] * w1;
        s2 += vh_l[nl][a * 3 + 1] * w1;
        s3 += vh_l[nl][a * 3 + 2] * w1;
    }
    int g = batch[n];
    float cM = fmaxf(cnt_s[g], 1.0f) * 32.0f;
    float mean = stat_s[0][g] / cM;
    float var = fmaxf(stat_s[1][g] / cM - mean * mean, 0.0f);
    float rs = rsqrtf(var + 1e-5f);
    float rv = rsqrtf(fmaxf(stat_s[2][g] / cM, 0.0f) + 1e-5f);

    size_t base = (size_t)n * 128;
    float z0 = out_b[base + z];
    out_b[base + z] = (z0 - mean) * rs * lnw0[z] + lnb0[z] + sk0 * INV32S + skb0[z];
    float lw = lnw1[z] * rv;
    float x0 = out_b[base + 32 + z * 3 + 0];
    float x1 = out_b[base + 32 + z * 3 + 1];
    float x2 = out_b[base + 32 + z * 3 + 2];
    out_b[base + 32 + z * 3 + 0] = x0 * lw + s1 * INV32S;
    out_b[base + 32 + z * 3 + 1] = x1 * lw + s2 * INV32S;
    out_b[base + 32 + z * 3 + 2] = x2 * lw + s3 * INV32S;
}

// ---------------------------------------------------------------------------
// Workspace layout (total = 2 MiB + 25.6 KiB for B=2):
//   tmp1  [0,       1 MiB)  : stageA out; REUSED as Weff (stageC out)
//   tmp2  [1 MiB,   2 MiB)  : stageB out; REUSED as bf16 packs (pack out)
//   cntb  [2 MiB, +1 KiB)   : cnt banks [NCBANK][16]
//   S1b/S2b/V2b             : stat banks [B][NBANK][16] each
// ---------------------------------------------------------------------------
extern "C" void kernel_launch(void* const* d_in, const int* in_sizes, int n_in,
                              void* d_out, int out_size, void* d_ws, size_t ws_size,
                              hipStream_t stream) {
    const float* hidden = (const float*)d_in[0];
    const float* up0    = (const float*)d_in[1];
    const float* hl_w0  = (const float*)d_in[2];
    const float* hl_w1  = (const float*)d_in[3];
    const float* ul_w0  = (const float*)d_in[4];
    const float* ul_w1  = (const float*)d_in[5];
    const float* w000   = (const float*)d_in[6];
    const float* w110   = (const float*)d_in[7];
    const float* w011   = (const float*)d_in[8];
    const float* w101   = (const float*)d_in[9];
    const float* lp_w0  = (const float*)d_in[10];
    const float* lp_b0  = (const float*)d_in[11];
    const float* lp_w1  = (const float*)d_in[12];
    const float* sc_w0  = (const float*)d_in[13];
    const float* sc_w1  = (const float*)d_in[14];
    const float* ln_w0  = (const float*)d_in[15];
    const float* ln_b0  = (const float*)d_in[16];
    const float* ln_w1  = (const float*)d_in[17];
    const float* sk_w0  = (const float*)d_in[18];
    const float* sk_b0  = (const float*)d_in[19];
    const float* sk_w1  = (const float*)d_in[20];
    const int* species  = (const int*)d_in[21];
    const int* batch    = (const int*)d_in[22];
    float* out = (float*)d_out;

    const int N = in_sizes[21];
    const int B = in_sizes[0] / (N * 128);

    float* ws = (float*)d_ws;
    float* tmp1 = ws;                                  // stageA out -> Weff
    float* tmp2 = tmp1 + (size_t)B * 4 * 32768;        // stageB out -> packs
    float* cntb = tmp2 + (size_t)B * 4 * 32768;        // [NCBANK][16]
    float* S1b = cntb + NCBANK * NGRAPH;               // [B][NBANK][16]
    float* S2b = S1b + (size_t)B * NBANK * NGRAPH;
    float* V2b = S2b + (size_t)B * NBANK * NGRAPH;
    int statn = NCBANK * NGRAPH + 3 * B * NBANK * NGRAPH;

    zero_kernel<<<(statn + 255) / 256, 256, 0, stream>>>(cntb, statn);
    count_kernel<<<(N + 255) / 256, 256, 0, stream>>>(batch, cntb, N);

    int nb = B * 4 * 32768 / 256;
    stageA_kernel<<<nb, 256, 0, stream>>>(w000, w110, w011, w101, lp_w0, lp_w1, tmp1);
    stageB_kernel<<<nb, 256, 0, stream>>>(ul_w0, ul_w1, tmp1, tmp2);
    stageC_kernel<<<nb, 256, 0, stream>>>(hl_w0, hl_w1, tmp2, tmp1);   // Weff -> tmp1

    u16* packs = (u16*)tmp2;                           // tmp2 dead after stageC
    int ptotal = B * 151552;
    pack_kernel<<<(ptotal + 255) / 256, 256, 0, stream>>>(tmp1, sc_w0, sc_w1, packs, ptotal);

    for (int b = 0; b < B; ++b) {
        const float* up = (b == 0) ? up0 : out + (size_t)(b - 1) * N * 128;
        const u16* pb = packs + (size_t)b * 151552;
        tp_kernel<<<(N + 31) / 32, 256, 0, stream>>>(
            hidden + (size_t)b * N * 128, up, pb,
            lp_b0 + b * MULT, species, batch,
            S1b + (size_t)b * NBANK * NGRAPH, S2b + (size_t)b * NBANK * NGRAPH,
            V2b + (size_t)b * NBANK * NGRAPH,
            out + (size_t)b * N * 128, N);
        norm_kernel<<<(N + 7) / 8, 256, 0, stream>>>(
            hidden + (size_t)b * N * 128, out + (size_t)b * N * 128,
            sk_w0 + b * 1024, sk_b0 + b * MULT, sk_w1 + b * 1024,
            ln_w0 + b * MULT, ln_b0 + b * MULT, ln_w1 + b * MULT,
            batch, S1b + (size_t)b * NBANK * NGRAPH, S2b + (size_t)b * NBANK * NGRAPH,
            V2b + (size_t)b * NBANK * NGRAPH, cntb, N);
    }
}